// Round 14
// baseline (371.477 us; speedup 1.0000x reference)
//
#include <hip/hip_runtime.h>
#include <hip/hip_bf16.h>
#include <hip/hip_fp16.h>

#define NN 100000
#define NG 256
#define NE 800000

constexpr int F0 = 114;   // x features
constexpr int F1 = 230;   // layer1 output features
constexpr int F2 = 115;   // layer2 output features
constexpr int MPAD = 100096;  // 1564 * 64

typedef _Float16 __attribute__((ext_vector_type(8))) f16x8;   // MFMA operand
typedef __attribute__((ext_vector_type(4))) float f32x4;      // MFMA acc
typedef __attribute__((ext_vector_type(8))) unsigned short u16x8;

__device__ __forceinline__ unsigned short f2h_bits(float x) {
  _Float16 h = (_Float16)x;
  return __builtin_bit_cast(unsigned short, h);
}
__device__ __forceinline__ float h_bits2f(unsigned short u) {
  return (float)__builtin_bit_cast(_Float16, u);
}

// ---------------- degree / CSR build ----------------

__global__ void k_count(const int* __restrict__ dst, int* __restrict__ cnt) {
  int e = blockIdx.x * blockDim.x + threadIdx.x;
  if (e < NE) atomicAdd(&cnt[dst[e]], 1);
}

constexpr int SCAN_T = 256;
constexpr int SCAN_E = 1024;
constexpr int NB = (NN + SCAN_E - 1) / SCAN_E;  // 98

// scan1 also emits dinv (fused former k_dinv)
__global__ void k_scan1(const int* __restrict__ cnt, int* __restrict__ off,
                        int* __restrict__ bsum, float* __restrict__ dinv) {
  __shared__ int s[SCAN_T];
  int b = blockIdx.x, t = threadIdx.x;
  int base = b * SCAN_E + t * 4;
  int v0 = 0, v1 = 0, v2 = 0, v3 = 0;
  if (base + 0 < NN) v0 = cnt[base + 0];
  if (base + 1 < NN) v1 = cnt[base + 1];
  if (base + 2 < NN) v2 = cnt[base + 2];
  if (base + 3 < NN) v3 = cnt[base + 3];
  if (base + 0 < NN) dinv[base + 0] = rsqrtf((float)v0 + 1.0f);
  if (base + 1 < NN) dinv[base + 1] = rsqrtf((float)v1 + 1.0f);
  if (base + 2 < NN) dinv[base + 2] = rsqrtf((float)v2 + 1.0f);
  if (base + 3 < NN) dinv[base + 3] = rsqrtf((float)v3 + 1.0f);
  int sum = v0 + v1 + v2 + v3;
  s[t] = sum;
  __syncthreads();
  for (int ofs = 1; ofs < SCAN_T; ofs <<= 1) {
    int x = (t >= ofs) ? s[t - ofs] : 0;
    __syncthreads();
    s[t] += x;
    __syncthreads();
  }
  int excl = s[t] - sum;
  if (base + 0 < NN) off[base + 0] = excl;
  if (base + 1 < NN) off[base + 1] = excl + v0;
  if (base + 2 < NN) off[base + 2] = excl + v0 + v1;
  if (base + 3 < NN) off[base + 3] = excl + v0 + v1 + v2;
  if (t == SCAN_T - 1) bsum[b] = s[t];
}

// wave-parallel exclusive scan of the 98 block sums
__global__ void k_scan2(int* bsum) {
  __shared__ int ws[2];
  int t = threadIdx.x;  // 128
  int v = (t < NB) ? bsum[t] : 0;
  int orig = v;
  for (int o = 1; o < 64; o <<= 1) {
    int x = __shfl_up(v, o, 64);
    if ((t & 63) >= o) v += x;
  }
  if ((t & 63) == 63) ws[t >> 6] = v;
  __syncthreads();
  if (t >= 64) v += ws[0];
  if (t < NB) bsum[t] = v - orig;
}

__global__ void k_scan3(int* __restrict__ off, const int* __restrict__ bsum,
                        int* __restrict__ cur) {
  int i = blockIdx.x * blockDim.x + threadIdx.x;
  if (i < NN) {
    int v = off[i] + bsum[i / SCAN_E];
    off[i] = v;
    cur[i] = v;
  }
  if (i == NN) off[NN] = NE;
}

__global__ void k_place(const int* __restrict__ src, const int* __restrict__ dst,
                        int* __restrict__ cur, int* __restrict__ srcs) {
  int e = blockIdx.x * blockDim.x + threadIdx.x;
  if (e >= NE) return;
  int p = atomicAdd(&cur[dst[e]], 1);
  srcs[p] = src[e];
}

// ---------------- fp16 tables ----------------

__global__ void k_prepx(const float* __restrict__ x, const float* __restrict__ dinv,
                        unsigned short* __restrict__ xd) {
  int n = blockIdx.x, f = threadIdx.x;  // 128 threads
  float v = (f < F0) ? x[(size_t)n * F0 + f] * dinv[n] : 0.0f;
  xd[(size_t)n * 128 + f] = f2h_bits(v);
}

// ---------------- wave-per-node gather+pool (layer 2 tail) ----------------

__global__ __launch_bounds__(256) void k_gatherw(
    const unsigned short* __restrict__ tab, const float* __restrict__ dinv,
    const int* __restrict__ off, const int* __restrict__ srcs,
    const float* __restrict__ b2, const int* __restrict__ batch,
    float* __restrict__ pooled) {
  __shared__ float smax[4][128];
  __shared__ int sg[4];
  int w = threadIdx.x >> 6, lane = threadIdx.x & 63;
  int n = blockIdx.x * 4 + w;
  int grp = lane >> 4, sub = lane & 15;
  int fb = sub * 8;

  float acc[8] = {0.f, 0.f, 0.f, 0.f, 0.f, 0.f, 0.f, 0.f};
  int j0 = off[n], j1 = off[n + 1];  // slots j0..j1, self at j1
  for (int base = j0; base <= j1; base += 16) {
    int row[4];
    u16x8 v[4];
    bool has[4];
#pragma unroll
    for (int c = 0; c < 4; ++c) {
      int je = base + c * 4 + grp;
      row[c] = (je < j1) ? srcs[je] : ((je == j1) ? n : -1);
      has[c] = row[c] >= 0;
    }
#pragma unroll
    for (int c = 0; c < 4; ++c)
      if (has[c]) v[c] = *(const u16x8*)&tab[(size_t)row[c] * 128 + fb];
#pragma unroll
    for (int c = 0; c < 4; ++c)
      if (has[c]) {
#pragma unroll
        for (int u = 0; u < 8; ++u) acc[u] += h_bits2f(v[c][u]);
      }
  }
#pragma unroll
  for (int u = 0; u < 8; ++u) {
    acc[u] += __shfl_xor(acc[u], 16);
    acc[u] += __shfl_xor(acc[u], 32);
  }
  float dn = dinv[n];

  if (grp == 0) {
#pragma unroll
    for (int u = 0; u < 8; ++u) {
      int f = fb + u;
      float bb = (f < F2) ? b2[f] : 0.0f;
      smax[w][f] = fmaxf(acc[u] * dn + bb, 0.0f);
    }
    if (sub == 0) sg[w] = batch[n];
  }
  __syncthreads();
  int t = threadIdx.x;
  if (t < 128) {
    int g0 = sg[0];
    bool same = (sg[1] == g0) & (sg[2] == g0) & (sg[3] == g0);
    if (same) {
      float m = fmaxf(fmaxf(smax[0][t], smax[1][t]),
                      fmaxf(smax[2][t], smax[3][t]));
      if (t < F2 && m > 0.0f)
        atomicMax((int*)&pooled[g0 * F2 + t], __float_as_int(m));
    } else {
      for (int ww = 0; ww < 4; ++ww) {
        float m = smax[ww][t];
        if (t < F2 && m > 0.0f)
          atomicMax((int*)&pooled[sg[ww] * F2 + t], __float_as_int(m));
      }
    }
  }
}

// ---------------- weight split+transpose prep (both matrices, one launch) ----

__global__ void k_prepB2(const float* __restrict__ W1, const float* __restrict__ W2,
                         unsigned short* __restrict__ B1h, unsigned short* __restrict__ B1l,
                         unsigned short* __restrict__ B2h, unsigned short* __restrict__ B2l) {
  int b = blockIdx.x, t = threadIdx.x;  // 256 threads
  if (b < 128) {  // B1: [256 n][128 k], two n-rows per block
    int n = b * 2 + (t >> 7), k = t & 127;
    float v = (k < F0 && n < F1) ? W1[(size_t)k * F1 + n] : 0.0f;
    unsigned short h = f2h_bits(v);
    unsigned short l = f2h_bits(v - h_bits2f(h));
    B1h[(size_t)n * 128 + k] = h;
    B1l[(size_t)n * 128 + k] = l;
  } else {        // B2: [128 n][256 k]
    int n = b - 128, k = t;
    float v = (k < F1 && n < F2) ? W2[(size_t)k * F2 + n] : 0.0f;
    unsigned short h = f2h_bits(v);
    unsigned short l = f2h_bits(v - h_bits2f(h));
    B2h[(size_t)n * 256 + k] = h;
    B2l[(size_t)n * 256 + k] = l;
  }
}

// ---------------- mega kernel: gather1 + double GEMM fused -------------------
// Per 64-row block: (0) gather aggX rows (fp16) straight into A-LDS;
// (1) h1B = fp16(relu(A @ W1t^T + b1)) in LDS; (2) acc2 = h1B @ W2t^T;
// epilogue *dinv, fp16 coalesced store to td. h1 and aggX never touch HBM.
// LDS: h1B 32K + A 16K + Bs 2x16K = 80 KB -> 2 blocks/CU. Swizzle byte^=(row&7)<<4.
// Memory-bound gather phase of one block overlaps MFMA phase of the co-resident
// block (m114 wave-level overlap).

__global__ __launch_bounds__(256) void k_mega(
    const unsigned short* __restrict__ xd, const float* __restrict__ dinv,
    const int* __restrict__ off, const int* __restrict__ srcs,
    const unsigned short* __restrict__ B1h, const unsigned short* __restrict__ B1l,
    const unsigned short* __restrict__ B2h, const unsigned short* __restrict__ B2l,
    const float* __restrict__ b1,
    unsigned short* __restrict__ td) {                                      // [MPAD][128]
  __shared__ char lds[81920];
  char* h1B = lds;            // 32768 B: 64 rows x 512 B (256 fp16 cols, swizzled)
  char* AsB = lds + 32768;    // 16384 B: 64 rows x 256 B (128 fp16 k, swizzled)
  char* Bs0 = lds + 49152;    // 16384 B: 128 rows x 128 B (hi)
  char* Bs1 = lds + 65536;    // (lo)

  const int t = threadIdx.x;
  const int m0 = blockIdx.x * 64;
  const int lane = t & 63, w = t >> 6;
  const int r = lane & 15;
  const int kq = lane >> 4;          // k-quarter 0..3
  const int kb16 = kq * 16;          // byte offset of lane's 16B k-frag in 128B
  const int rq = kq * 4;
  const int wc = w * 32;             // wave's 32-col slice
  const int swr = (r & 7) << 4;      // MFMA-read swizzle
  const int grp = kq, sub = r;       // gather roles: 4 groups x 16 lanes
  const int fb = sub * 8;            // fp16 col base for this lane
  const int brow = t >> 1, bseg = t & 1, bswz = (brow & 7) << 4;

  // ---------- phase 0: gather aggX rows into A-LDS ----------
  for (int i = 0; i < 16; ++i) {
    const int row = w * 16 + i;
    const int n = m0 + row;
    float acc[8] = {0.f, 0.f, 0.f, 0.f, 0.f, 0.f, 0.f, 0.f};
    if (n < NN) {
      const int j0 = off[n], j1 = off[n + 1];  // self at j1
      for (int base = j0; base <= j1; base += 16) {
        int rw[4];
        u16x8 v[4];
        bool has[4];
#pragma unroll
        for (int c = 0; c < 4; ++c) {
          int je = base + c * 4 + grp;
          rw[c] = (je < j1) ? srcs[je] : ((je == j1) ? n : -1);
          has[c] = rw[c] >= 0;
        }
#pragma unroll
        for (int c = 0; c < 4; ++c)
          if (has[c]) v[c] = *(const u16x8*)&xd[(size_t)rw[c] * 128 + fb];
#pragma unroll
        for (int c = 0; c < 4; ++c)
          if (has[c]) {
#pragma unroll
            for (int u = 0; u < 8; ++u) acc[u] += h_bits2f(v[c][u]);
          }
      }
#pragma unroll
      for (int u = 0; u < 8; ++u) {
        acc[u] += __shfl_xor(acc[u], 16);
        acc[u] += __shfl_xor(acc[u], 32);
      }
      const float dn = dinv[n];
#pragma unroll
      for (int u = 0; u < 8; ++u) acc[u] *= dn;
    }
    if (grp == 0) {  // pad rows (n>=NN) write zeros
      u16x8 o;
#pragma unroll
      for (int u = 0; u < 8; ++u) o[u] = f2h_bits(acc[u]);
      *(u16x8*)(AsB + row * 256 + ((sub * 16) ^ ((row & 7) << 4))) = o;
    }
  }
  __syncthreads();

  // ---------- stage 1: h1B = fp16(relu(A @ W1t^T + b1)), 256 cols ----------
  for (int h = 0; h < 2; ++h) {
    f32x4 acc[4][2];
#pragma unroll
    for (int i = 0; i < 4; ++i)
#pragma unroll
      for (int j = 0; j < 2; ++j) acc[i][j] = (f32x4){0.f, 0.f, 0.f, 0.f};

    for (int kc = 0; kc < 2; ++kc) {
      if (h | kc) __syncthreads();  // Bs free (previous consumers done)
      {
        size_t gb = (size_t)(h * 128 + brow) * 128 + kc * 64 + bseg * 32;
#pragma unroll
        for (int v = 0; v < 4; ++v) {
          const int bo = (bseg * 64 + v * 16) ^ bswz;
          *(u16x8*)(Bs0 + brow * 128 + bo) = *(const u16x8*)&B1h[gb + v * 8];
          *(u16x8*)(Bs1 + brow * 128 + bo) = *(const u16x8*)&B1l[gb + v * 8];
        }
      }
      __syncthreads();
#pragma unroll
      for (int ks = 0; ks < 2; ++ks) {
        f16x8 av[4], bh[2], bl[2];
#pragma unroll
        for (int i = 0; i < 4; ++i)
          av[i] = *(const f16x8*)(AsB + (i * 16 + r) * 256 +
                                  ((kc * 128 + ks * 64 + kb16) ^ swr));
#pragma unroll
        for (int j = 0; j < 2; ++j) {
          const int row = wc + j * 16 + r;
          const int bo = (ks * 64 + kb16) ^ swr;
          bh[j] = *(const f16x8*)(Bs0 + row * 128 + bo);
          bl[j] = *(const f16x8*)(Bs1 + row * 128 + bo);
        }
#pragma unroll
        for (int i = 0; i < 4; ++i)
#pragma unroll
          for (int j = 0; j < 2; ++j)
            acc[i][j] = __builtin_amdgcn_mfma_f32_16x16x32_f16(av[i], bl[j], acc[i][j], 0, 0, 0);
#pragma unroll
        for (int i = 0; i < 4; ++i)
#pragma unroll
          for (int j = 0; j < 2; ++j)
            acc[i][j] = __builtin_amdgcn_mfma_f32_16x16x32_f16(av[i], bh[j], acc[i][j], 0, 0, 0);
      }
    }

    // bias+relu -> h1B (swizzled; h halves write disjoint byte ranges)
    // C/D layout: col = lane&15 (n), row = kq*4 + q (m)  [m89/m91]
#pragma unroll
    for (int i = 0; i < 4; ++i)
#pragma unroll
      for (int j = 0; j < 2; ++j) {
        const int nl = wc + j * 16 + r;
        const int n = h * 128 + nl;
        const bool val = n < F1;
        const float bb = val ? b1[n] : 0.0f;
#pragma unroll
        for (int q = 0; q < 4; ++q) {
          const int ml = i * 16 + rq + q;
          const float v = val ? fmaxf(acc[i][j][q] + bb, 0.0f) : 0.0f;
          *(unsigned short*)(h1B + ml * 512 + ((n * 2) ^ ((ml & 7) << 4))) = f2h_bits(v);
        }
      }
  }

  // ---------- stage 2: acc2 = (h1B @ W2t^T), K = 256 ----------
  f32x4 acc2[4][2];
#pragma unroll
  for (int i = 0; i < 4; ++i)
#pragma unroll
    for (int j = 0; j < 2; ++j) acc2[i][j] = (f32x4){0.f, 0.f, 0.f, 0.f};

  for (int kc = 0; kc < 4; ++kc) {
    __syncthreads();  // kc=0 also fences h1B writes
    {
      size_t gb = (size_t)brow * 256 + kc * 64 + bseg * 32;
#pragma unroll
      for (int v = 0; v < 4; ++v) {
        const int bo = (bseg * 64 + v * 16) ^ bswz;
        *(u16x8*)(Bs0 + brow * 128 + bo) = *(const u16x8*)&B2h[gb + v * 8];
        *(u16x8*)(Bs1 + brow * 128 + bo) = *(const u16x8*)&B2l[gb + v * 8];
      }
    }
    __syncthreads();
#pragma unroll
    for (int ks = 0; ks < 2; ++ks) {
      f16x8 ah[4], bh[2], bl[2];
#pragma unroll
      for (int i = 0; i < 4; ++i) {
        const int row = i * 16 + r;
        ah[i] = *(const f16x8*)(h1B + row * 512 + ((kc * 128 + ks * 64 + kb16) ^ swr));
      }
#pragma unroll
      for (int j = 0; j < 2; ++j) {
        const int row = wc + j * 16 + r;
        const int bo = (ks * 64 + kb16) ^ swr;
        bh[j] = *(const f16x8*)(Bs0 + row * 128 + bo);
        bl[j] = *(const f16x8*)(Bs1 + row * 128 + bo);
      }
#pragma unroll
      for (int i = 0; i < 4; ++i)
#pragma unroll
        for (int j = 0; j < 2; ++j)
          acc2[i][j] = __builtin_amdgcn_mfma_f32_16x16x32_f16(ah[i], bl[j], acc2[i][j], 0, 0, 0);
#pragma unroll
      for (int i = 0; i < 4; ++i)
#pragma unroll
        for (int j = 0; j < 2; ++j)
          acc2[i][j] = __builtin_amdgcn_mfma_f32_16x16x32_f16(ah[i], bh[j], acc2[i][j], 0, 0, 0);
    }
  }

  // epilogue: scale by dinv[m], stage fp16 tile into h1B (swizzled), store
  __syncthreads();  // all h1B reads done
#pragma unroll
  for (int i = 0; i < 4; ++i)
#pragma unroll
    for (int j = 0; j < 2; ++j) {
      const int nl = wc + j * 16 + r;
#pragma unroll
      for (int q = 0; q < 4; ++q) {
        const int ml = i * 16 + rq + q;
        const int m = m0 + ml;
        const float ds = (m < NN) ? dinv[m] : 0.0f;
        const float v = acc2[i][j][q] * ds;
        *(unsigned short*)(h1B + ml * 512 + ((nl * 2) ^ ((ml & 7) << 4))) = f2h_bits(v);
      }
    }
  __syncthreads();
  {
    const int row = t >> 2, seg = t & 3;
    const int swz = (row & 7) << 4;
    const size_t dst = (size_t)(m0 + row) * 128 + seg * 32;
#pragma unroll
    for (int v = 0; v < 4; ++v) {
      u16x8 d = *(const u16x8*)(h1B + row * 512 + ((seg * 64 + v * 16) ^ swz));
      *(u16x8*)&td[dst + v * 8] = d;
    }
  }
}

// ---------------- tiny MLP head: 115 -> 64 -> 32 -> 1 ----------------

__global__ void k_mlp(const float* __restrict__ pooled,
                      const float* __restrict__ Wg, const float* __restrict__ bg,
                      const float* __restrict__ Wf, const float* __restrict__ bf,
                      const float* __restrict__ Wo, const float* __restrict__ bo,
                      float* __restrict__ out) {
  __shared__ float sp[F2];
  __shared__ float sg[64];
  __shared__ float sf[32];
  int g = blockIdx.x, t = threadIdx.x;
  for (int f = t; f < F2; f += 64) sp[f] = pooled[g * F2 + f];
  __syncthreads();
  float a = bg[t];
  for (int k = 0; k < F2; ++k) a += sp[k] * Wg[k * 64 + t];
  sg[t] = fmaxf(a, 0.0f);
  __syncthreads();
  if (t < 32) {
    float c = bf[t];
    for (int k = 0; k < 64; ++k) c += sg[k] * Wf[k * 32 + t];
    sf[t] = fmaxf(c, 0.0f);
  }
  __syncthreads();
  if (t == 0) {
    float c = bo[0];
    for (int k = 0; k < 32; ++k) c += sf[k] * Wo[k];
    out[g] = c;
  }
}

// ---------------- launch ----------------

extern "C" void kernel_launch(void* const* d_in, const int* in_sizes, int n_in,
                              void* d_out, int out_size, void* d_ws, size_t ws_size,
                              hipStream_t stream) {
  const float* x  = (const float*)d_in[0];
  const int* ei   = (const int*)d_in[1];
  const int* batch = (const int*)d_in[2];
  const float* W1 = (const float*)d_in[3];
  const float* b1 = (const float*)d_in[4];
  const float* W2 = (const float*)d_in[5];
  const float* b2 = (const float*)d_in[6];
  const float* Wg = (const float*)d_in[7];
  const float* bg = (const float*)d_in[8];
  const float* Wf = (const float*)d_in[9];
  const float* bf = (const float*)d_in[10];
  const float* Wo = (const float*)d_in[11];
  const float* bo = (const float*)d_in[12];
  const int* src = ei;
  const int* dst = ei + NE;

  char* p = (char*)d_ws;
  auto alloc4 = [&](size_t units) { void* r = p; p += units * 4; return r; };
  float* dinv  = (float*)alloc4(100224);
  int* cnt     = (int*)alloc4(100224);
  int* off     = (int*)alloc4(100352);
  int* cur     = (int*)alloc4(100224);
  int* bsum    = (int*)alloc4(128);
  int* srcs    = (int*)alloc4(NE);
  unsigned short* xd   = (unsigned short*)alloc4((size_t)NN * 128 / 2);    // 25.6MB
  unsigned short* td   = (unsigned short*)alloc4((size_t)MPAD * 128 / 2);  // 25.6MB
  unsigned short* Bt1h = (unsigned short*)alloc4(256 * 128 / 2);
  unsigned short* Bt1l = (unsigned short*)alloc4(256 * 128 / 2);
  unsigned short* Bt2h = (unsigned short*)alloc4(128 * 256 / 2);
  unsigned short* Bt2l = (unsigned short*)alloc4(128 * 256 / 2);
  float* pooled = (float*)alloc4((size_t)NG * F2);

  hipMemsetAsync(cnt, 0, 100224 * sizeof(int), stream);
  hipMemsetAsync(pooled, 0, (size_t)NG * F2 * sizeof(float), stream);

  // CSR build (shared by both conv layers); scan1 also emits dinv
  k_count<<<(NE + 255) / 256, 256, 0, stream>>>(dst, cnt);
  k_scan1<<<NB, SCAN_T, 0, stream>>>(cnt, off, bsum, dinv);
  k_scan2<<<1, 128, 0, stream>>>(bsum);
  k_scan3<<<(NN + 256) / 256, 256, 0, stream>>>(off, bsum, cur);
  k_place<<<(NE + 255) / 256, 256, 0, stream>>>(src, dst, cur, srcs);

  // weight prep (fp16 hi/lo, transposed, zero-padded) — single launch
  k_prepB2<<<256, 256, 0, stream>>>(W1, W2, Bt1h, Bt1l, Bt2h, Bt2l);

  // fp16 x*dinv table
  k_prepx<<<NN, 128, 0, stream>>>(x, dinv, xd);

  // mega: per-block gather1 -> LDS A -> conv1 GEMM -> LDS h1 -> conv2 GEMM -> td
  k_mega<<<MPAD / 64, 256, 0, stream>>>(xd, dinv, off, srcs,
                                        Bt1h, Bt1l, Bt2h, Bt2l, b1, td);

  // layer 2 aggregation fused with relu(+b2) + per-graph max pool
  k_gatherw<<<NN / 4, 256, 0, stream>>>(td, dinv, off, srcs, b2, batch, pooled);

  // head MLP
  k_mlp<<<NG, 64, 0, stream>>>(pooled, Wg, bg, Wf, bf, Wo, bo, (float*)d_out);
}

// Round 15
// 302.443 us; speedup vs baseline: 1.2283x; 1.2283x over previous
//
#include <hip/hip_runtime.h>
#include <hip/hip_bf16.h>
#include <hip/hip_fp16.h>

#define NN 100000
#define NG 256
#define NE 800000

constexpr int F0 = 114;   // x features
constexpr int F1 = 230;   // layer1 output features
constexpr int F2 = 115;   // layer2 output features
constexpr int MPAD = 100096;  // 1564 * 64

typedef _Float16 __attribute__((ext_vector_type(8))) f16x8;   // MFMA operand
typedef __attribute__((ext_vector_type(4))) float f32x4;      // MFMA acc
typedef __attribute__((ext_vector_type(8))) unsigned short u16x8;

__device__ __forceinline__ unsigned short f2h_bits(float x) {
  _Float16 h = (_Float16)x;
  return __builtin_bit_cast(unsigned short, h);
}
__device__ __forceinline__ float h_bits2f(unsigned short u) {
  return (float)__builtin_bit_cast(_Float16, u);
}

// ---------------- degree / CSR build ----------------

__global__ void k_count(const int* __restrict__ dst, int* __restrict__ cnt) {
  int e = blockIdx.x * blockDim.x + threadIdx.x;
  if (e < NE) atomicAdd(&cnt[dst[e]], 1);
}

constexpr int SCAN_T = 256;
constexpr int SCAN_E = 1024;
constexpr int NB = (NN + SCAN_E - 1) / SCAN_E;  // 98

// scan1 also emits dinv (fused former k_dinv)
__global__ void k_scan1(const int* __restrict__ cnt, int* __restrict__ off,
                        int* __restrict__ bsum, float* __restrict__ dinv) {
  __shared__ int s[SCAN_T];
  int b = blockIdx.x, t = threadIdx.x;
  int base = b * SCAN_E + t * 4;
  int v0 = 0, v1 = 0, v2 = 0, v3 = 0;
  if (base + 0 < NN) v0 = cnt[base + 0];
  if (base + 1 < NN) v1 = cnt[base + 1];
  if (base + 2 < NN) v2 = cnt[base + 2];
  if (base + 3 < NN) v3 = cnt[base + 3];
  if (base + 0 < NN) dinv[base + 0] = rsqrtf((float)v0 + 1.0f);
  if (base + 1 < NN) dinv[base + 1] = rsqrtf((float)v1 + 1.0f);
  if (base + 2 < NN) dinv[base + 2] = rsqrtf((float)v2 + 1.0f);
  if (base + 3 < NN) dinv[base + 3] = rsqrtf((float)v3 + 1.0f);
  int sum = v0 + v1 + v2 + v3;
  s[t] = sum;
  __syncthreads();
  for (int ofs = 1; ofs < SCAN_T; ofs <<= 1) {
    int x = (t >= ofs) ? s[t - ofs] : 0;
    __syncthreads();
    s[t] += x;
    __syncthreads();
  }
  int excl = s[t] - sum;
  if (base + 0 < NN) off[base + 0] = excl;
  if (base + 1 < NN) off[base + 1] = excl + v0;
  if (base + 2 < NN) off[base + 2] = excl + v0 + v1;
  if (base + 3 < NN) off[base + 3] = excl + v0 + v1 + v2;
  if (t == SCAN_T - 1) bsum[b] = s[t];
}

// wave-parallel exclusive scan of the 98 block sums
__global__ void k_scan2(int* bsum) {
  __shared__ int ws[2];
  int t = threadIdx.x;  // 128
  int v = (t < NB) ? bsum[t] : 0;
  int orig = v;
  for (int o = 1; o < 64; o <<= 1) {
    int x = __shfl_up(v, o, 64);
    if ((t & 63) >= o) v += x;
  }
  if ((t & 63) == 63) ws[t >> 6] = v;
  __syncthreads();
  if (t >= 64) v += ws[0];
  if (t < NB) bsum[t] = v - orig;
}

__global__ void k_scan3(int* __restrict__ off, const int* __restrict__ bsum,
                        int* __restrict__ cur) {
  int i = blockIdx.x * blockDim.x + threadIdx.x;
  if (i < NN) {
    int v = off[i] + bsum[i / SCAN_E];
    off[i] = v;
    cur[i] = v;
  }
  if (i == NN) off[NN] = NE;
}

__global__ void k_place(const int* __restrict__ src, const int* __restrict__ dst,
                        int* __restrict__ cur, int* __restrict__ srcs) {
  int e = blockIdx.x * blockDim.x + threadIdx.x;
  if (e >= NE) return;
  int p = atomicAdd(&cur[dst[e]], 1);
  srcs[p] = src[e];
}

// ---------------- fp16 tables ----------------

__global__ void k_prepx(const float* __restrict__ x, const float* __restrict__ dinv,
                        unsigned short* __restrict__ xd) {
  int n = blockIdx.x, f = threadIdx.x;  // 128 threads
  float v = (f < F0) ? x[(size_t)n * F0 + f] * dinv[n] : 0.0f;
  xd[(size_t)n * 128 + f] = f2h_bits(v);
}

// ---------------- wave-per-node gather: 16 edge slots/iter, 4 loads in flight

template <bool POOL>
__global__ __launch_bounds__(256) void k_gatherw(
    const unsigned short* __restrict__ tab, const float* __restrict__ dinv,
    const int* __restrict__ off, const int* __restrict__ srcs,
    const float* __restrict__ b2, const int* __restrict__ batch,
    unsigned short* __restrict__ outh, float* __restrict__ pooled) {
  __shared__ float smax[4][128];
  __shared__ int sg[4];
  int w = threadIdx.x >> 6, lane = threadIdx.x & 63;
  int n = blockIdx.x * 4 + w;
  int grp = lane >> 4, sub = lane & 15;
  int fb = sub * 8;

  float acc[8] = {0.f, 0.f, 0.f, 0.f, 0.f, 0.f, 0.f, 0.f};
  int j0 = off[n], j1 = off[n + 1];  // slots j0..j1, self at j1
  for (int base = j0; base <= j1; base += 16) {
    int row[4];
    u16x8 v[4];
    bool has[4];
#pragma unroll
    for (int c = 0; c < 4; ++c) {
      int je = base + c * 4 + grp;
      row[c] = (je < j1) ? srcs[je] : ((je == j1) ? n : -1);
      has[c] = row[c] >= 0;
    }
#pragma unroll
    for (int c = 0; c < 4; ++c)
      if (has[c]) v[c] = *(const u16x8*)&tab[(size_t)row[c] * 128 + fb];
#pragma unroll
    for (int c = 0; c < 4; ++c)
      if (has[c]) {
#pragma unroll
        for (int u = 0; u < 8; ++u) acc[u] += h_bits2f(v[c][u]);
      }
  }
#pragma unroll
  for (int u = 0; u < 8; ++u) {
    acc[u] += __shfl_xor(acc[u], 16);
    acc[u] += __shfl_xor(acc[u], 32);
  }
  float dn = dinv[n];

  if constexpr (!POOL) {
    if (grp == 0) {
      u16x8 o;
#pragma unroll
      for (int u = 0; u < 8; ++u) o[u] = f2h_bits(acc[u] * dn);
      *(u16x8*)&outh[(size_t)n * 128 + fb] = o;
    }
  } else {
    if (grp == 0) {
#pragma unroll
      for (int u = 0; u < 8; ++u) {
        int f = fb + u;
        float bb = (f < F2) ? b2[f] : 0.0f;
        smax[w][f] = fmaxf(acc[u] * dn + bb, 0.0f);
      }
      if (sub == 0) sg[w] = batch[n];
    }
    __syncthreads();
    int t = threadIdx.x;
    if (t < 128) {
      int g0 = sg[0];
      bool same = (sg[1] == g0) & (sg[2] == g0) & (sg[3] == g0);
      if (same) {
        float m = fmaxf(fmaxf(smax[0][t], smax[1][t]),
                        fmaxf(smax[2][t], smax[3][t]));
        if (t < F2 && m > 0.0f)
          atomicMax((int*)&pooled[g0 * F2 + t], __float_as_int(m));
      } else {
        for (int ww = 0; ww < 4; ++ww) {
          float m = smax[ww][t];
          if (t < F2 && m > 0.0f)
            atomicMax((int*)&pooled[sg[ww] * F2 + t], __float_as_int(m));
        }
      }
    }
  }
}

// ---------------- weight split+transpose prep (both matrices, one launch) ----

__global__ void k_prepB2(const float* __restrict__ W1, const float* __restrict__ W2,
                         unsigned short* __restrict__ B1h, unsigned short* __restrict__ B1l,
                         unsigned short* __restrict__ B2h, unsigned short* __restrict__ B2l) {
  int b = blockIdx.x, t = threadIdx.x;  // 256 threads
  if (b < 128) {  // B1: [256 n][128 k], two n-rows per block
    int n = b * 2 + (t >> 7), k = t & 127;
    float v = (k < F0 && n < F1) ? W1[(size_t)k * F1 + n] : 0.0f;
    unsigned short h = f2h_bits(v);
    unsigned short l = f2h_bits(v - h_bits2f(h));
    B1h[(size_t)n * 128 + k] = h;
    B1l[(size_t)n * 128 + k] = l;
  } else {        // B2: [128 n][256 k]
    int n = b - 128, k = t;
    float v = (k < F1 && n < F2) ? W2[(size_t)k * F2 + n] : 0.0f;
    unsigned short h = f2h_bits(v);
    unsigned short l = f2h_bits(v - h_bits2f(h));
    B2h[(size_t)n * 256 + k] = h;
    B2l[(size_t)n * 256 + k] = l;
  }
}

// ---------------- fused double GEMM v5: td = (relu(aggX@W1t^T+b1) @ W2t^T)*dinv
// r13 structure + (1) A-tile staged ONCE in prologue (kills per-round HBM
// latency) and (2) B register-prefetch one round ahead (T3/T14 2-phase:
// commit pB -> issue pB(r+1) -> MFMA(r); B L2 latency overlaps MFMA).
// Plain launch_bounds (r11/r12's scratch came from the ,3 cap).
// LDS: h1B 32K + As 16K + Bs 2x16K = 80 KB -> 2 blocks/CU.
// Swizzle byte^=(row&7)<<4 (verified r13/r14, absmax must stay 4.88e-4).

__global__ __launch_bounds__(256) void k_fused(
    const unsigned short* __restrict__ A,                                   // [MPAD][128]
    const unsigned short* __restrict__ B1h, const unsigned short* __restrict__ B1l,  // [256][128]
    const unsigned short* __restrict__ B2h, const unsigned short* __restrict__ B2l,  // [128][256]
    const float* __restrict__ b1, const float* __restrict__ dscale,
    unsigned short* __restrict__ td) {                                      // [MPAD][128]
  __shared__ char lds[81920];
  char* h1B = lds;            // 32768 B: 64 rows x 512 B (256 fp16 cols, swizzled)
  char* AsB = lds + 32768;    // 16384 B: 64 rows x 256 B (128 fp16 k, swizzled)
  char* Bs0 = lds + 49152;    // 16384 B: 128 rows x 128 B (hi)
  char* Bs1 = lds + 65536;    // (lo)

  const int t = threadIdx.x;
  const int m0 = blockIdx.x * 64;
  const int lane = t & 63, w = t >> 6;
  const int r = lane & 15;
  const int kq = lane >> 4;          // k-quarter 0..3
  const int kb16 = kq * 16;          // byte offset of lane's 16B k-frag in 128B
  const int rq = kq * 4;
  const int wc = w * 32;             // wave's 32-col slice
  const int swr = (r & 7) << 4;      // MFMA-read swizzle
  const int arow = t >> 2, aseg = t & 3, aswz = (arow & 7) << 4;
  const int brow = t >> 1, bseg = t & 1, bswz = (brow & 7) << 4;

  // ---------- prologue: stage full A tile once; issue B(round 0) ----------
  {
    size_t ga = (size_t)(m0 + arow) * 128 + aseg * 32;
#pragma unroll
    for (int v = 0; v < 4; ++v) {
      u16x8 d = *(const u16x8*)&A[ga + v * 8];
      *(u16x8*)(AsB + arow * 256 + ((aseg * 64 + v * 16) ^ aswz)) = d;
    }
  }
  u16x8 ph[4], pl[4];
  {
    size_t gb = (size_t)brow * 128 + bseg * 32;  // B1, h=0, kc=0
#pragma unroll
    for (int v = 0; v < 4; ++v) {
      ph[v] = *(const u16x8*)&B1h[gb + v * 8];
      pl[v] = *(const u16x8*)&B1l[gb + v * 8];
    }
  }

  f32x4 acc1[4][2], acc2[4][2];
#pragma unroll
  for (int i = 0; i < 4; ++i)
#pragma unroll
    for (int j = 0; j < 2; ++j) {
      acc1[i][j] = (f32x4){0.f, 0.f, 0.f, 0.f};
      acc2[i][j] = (f32x4){0.f, 0.f, 0.f, 0.f};
    }

  // ---------- 8 pipelined rounds: 0..3 stage1 (h=rd>>1,kc=rd&1), 4..7 stage2
#pragma unroll
  for (int rd = 0; rd < 8; ++rd) {
    __syncthreads();  // prev round's Bs readers done; rd=0: fences AsB writes
    // commit prefetched B to LDS
#pragma unroll
    for (int v = 0; v < 4; ++v) {
      const int bo = (bseg * 64 + v * 16) ^ bswz;
      *(u16x8*)(Bs0 + brow * 128 + bo) = ph[v];
      *(u16x8*)(Bs1 + brow * 128 + bo) = pl[v];
    }
    // issue next round's B (overlaps this round's MFMA phase)
    if (rd < 7) {
      const int nr = rd + 1;
      const unsigned short* Gh = (nr < 4) ? B1h : B2h;
      const unsigned short* Gl = (nr < 4) ? B1l : B2l;
      const size_t gb = (nr < 4)
          ? (size_t)((nr >> 1) * 128 + brow) * 128 + (nr & 1) * 64 + bseg * 32
          : (size_t)brow * 256 + (nr - 4) * 64 + bseg * 32;
#pragma unroll
      for (int v = 0; v < 4; ++v) {
        ph[v] = *(const u16x8*)&Gh[gb + v * 8];
        pl[v] = *(const u16x8*)&Gl[gb + v * 8];
      }
    }
    __syncthreads();  // Bs ready

    if (rd < 4) {
      // ----- stage 1 MFMA: acc1 += A[:,kc*64..] @ B1-chunk -----
      const int kc = rd & 1;
#pragma unroll
      for (int ks = 0; ks < 2; ++ks) {
        f16x8 av[4], bh[2], bl[2];
#pragma unroll
        for (int i = 0; i < 4; ++i)
          av[i] = *(const f16x8*)(AsB + (i * 16 + r) * 256 +
                                  ((kc * 128 + ks * 64 + kb16) ^ swr));
#pragma unroll
        for (int j = 0; j < 2; ++j) {
          const int row = wc + j * 16 + r;
          const int bo = (ks * 64 + kb16) ^ swr;
          bh[j] = *(const f16x8*)(Bs0 + row * 128 + bo);
          bl[j] = *(const f16x8*)(Bs1 + row * 128 + bo);
        }
#pragma unroll
        for (int i = 0; i < 4; ++i)
#pragma unroll
          for (int j = 0; j < 2; ++j)
            acc1[i][j] = __builtin_amdgcn_mfma_f32_16x16x32_f16(av[i], bl[j], acc1[i][j], 0, 0, 0);
#pragma unroll
        for (int i = 0; i < 4; ++i)
#pragma unroll
          for (int j = 0; j < 2; ++j)
            acc1[i][j] = __builtin_amdgcn_mfma_f32_16x16x32_f16(av[i], bh[j], acc1[i][j], 0, 0, 0);
      }
      if (rd == 1 || rd == 3) {
        // bias+relu -> h1B (swizzled); read fenced by round-4 barrier
        // C/D layout: col = lane&15 (n), row = kq*4 + q (m)  [m89/m91]
        const int h = rd >> 1;
#pragma unroll
        for (int i = 0; i < 4; ++i)
#pragma unroll
          for (int j = 0; j < 2; ++j) {
            const int nl = wc + j * 16 + r;
            const int n = h * 128 + nl;
            const bool val = n < F1;
            const float bb = val ? b1[n] : 0.0f;
#pragma unroll
            for (int q = 0; q < 4; ++q) {
              const int ml = i * 16 + rq + q;
              const float v = val ? fmaxf(acc1[i][j][q] + bb, 0.0f) : 0.0f;
              *(unsigned short*)(h1B + ml * 512 + ((n * 2) ^ ((ml & 7) << 4))) = f2h_bits(v);
            }
          }
#pragma unroll
        for (int i = 0; i < 4; ++i)
#pragma unroll
          for (int j = 0; j < 2; ++j) acc1[i][j] = (f32x4){0.f, 0.f, 0.f, 0.f};
      }
    } else {
      // ----- stage 2 MFMA: acc2 += h1B[:,kc*64..] @ B2-chunk, K=256 -----
      const int kc = rd - 4;
#pragma unroll
      for (int ks = 0; ks < 2; ++ks) {
        f16x8 ah[4], bh[2], bl[2];
#pragma unroll
        for (int i = 0; i < 4; ++i) {
          const int row = i * 16 + r;
          ah[i] = *(const f16x8*)(h1B + row * 512 + ((kc * 128 + ks * 64 + kb16) ^ swr));
        }
#pragma unroll
        for (int j = 0; j < 2; ++j) {
          const int row = wc + j * 16 + r;
          const int bo = (ks * 64 + kb16) ^ swr;
          bh[j] = *(const f16x8*)(Bs0 + row * 128 + bo);
          bl[j] = *(const f16x8*)(Bs1 + row * 128 + bo);
        }
#pragma unroll
        for (int i = 0; i < 4; ++i)
#pragma unroll
          for (int j = 0; j < 2; ++j)
            acc2[i][j] = __builtin_amdgcn_mfma_f32_16x16x32_f16(ah[i], bl[j], acc2[i][j], 0, 0, 0);
#pragma unroll
        for (int i = 0; i < 4; ++i)
#pragma unroll
          for (int j = 0; j < 2; ++j)
            acc2[i][j] = __builtin_amdgcn_mfma_f32_16x16x32_f16(ah[i], bh[j], acc2[i][j], 0, 0, 0);
      }
    }
  }

  // epilogue: scale by dinv[m], stage fp16 tile into h1B (swizzled), store
  __syncthreads();  // all h1B reads done
#pragma unroll
  for (int i = 0; i < 4; ++i)
#pragma unroll
    for (int j = 0; j < 2; ++j) {
      const int nl = wc + j * 16 + r;
#pragma unroll
      for (int q = 0; q < 4; ++q) {
        const int ml = i * 16 + rq + q;
        const float v = acc2[i][j][q] * dscale[m0 + ml];
        *(unsigned short*)(h1B + ml * 512 + ((nl * 2) ^ ((ml & 7) << 4))) = f2h_bits(v);
      }
    }
  __syncthreads();
  {
    const int row = t >> 2, seg = t & 3;
    const int swz = (row & 7) << 4;
    const size_t dst = (size_t)(m0 + row) * 128 + seg * 32;
#pragma unroll
    for (int v = 0; v < 4; ++v) {
      u16x8 d = *(const u16x8*)(h1B + row * 512 + ((seg * 64 + v * 16) ^ swz));
      *(u16x8*)&td[dst + v * 8] = d;
    }
  }
}

// ---------------- tiny MLP head: 115 -> 64 -> 32 -> 1 ----------------

__global__ void k_mlp(const float* __restrict__ pooled,
                      const float* __restrict__ Wg, const float* __restrict__ bg,
                      const float* __restrict__ Wf, const float* __restrict__ bf,
                      const float* __restrict__ Wo, const float* __restrict__ bo,
                      float* __restrict__ out) {
  __shared__ float sp[F2];
  __shared__ float sg[64];
  __shared__ float sf[32];
  int g = blockIdx.x, t = threadIdx.x;
  for (int f = t; f < F2; f += 64) sp[f] = pooled[g * F2 + f];
  __syncthreads();
  float a = bg[t];
  for (int k = 0; k < F2; ++k) a += sp[k] * Wg[k * 64 + t];
  sg[t] = fmaxf(a, 0.0f);
  __syncthreads();
  if (t < 32) {
    float c = bf[t];
    for (int k = 0; k < 64; ++k) c += sg[k] * Wf[k * 32 + t];
    sf[t] = fmaxf(c, 0.0f);
  }
  __syncthreads();
  if (t == 0) {
    float c = bo[0];
    for (int k = 0; k < 32; ++k) c += sf[k] * Wo[k];
    out[g] = c;
  }
}

// ---------------- launch ----------------

extern "C" void kernel_launch(void* const* d_in, const int* in_sizes, int n_in,
                              void* d_out, int out_size, void* d_ws, size_t ws_size,
                              hipStream_t stream) {
  const float* x  = (const float*)d_in[0];
  const int* ei   = (const int*)d_in[1];
  const int* batch = (const int*)d_in[2];
  const float* W1 = (const float*)d_in[3];
  const float* b1 = (const float*)d_in[4];
  const float* W2 = (const float*)d_in[5];
  const float* b2 = (const float*)d_in[6];
  const float* Wg = (const float*)d_in[7];
  const float* bg = (const float*)d_in[8];
  const float* Wf = (const float*)d_in[9];
  const float* bf = (const float*)d_in[10];
  const float* Wo = (const float*)d_in[11];
  const float* bo = (const float*)d_in[12];
  const int* src = ei;
  const int* dst = ei + NE;

  char* p = (char*)d_ws;
  auto alloc4 = [&](size_t units) { void* r = p; p += units * 4; return r; };
  float* dinv  = (float*)alloc4(100224);
  int* cnt     = (int*)alloc4(100224);
  int* off     = (int*)alloc4(100352);
  int* cur     = (int*)alloc4(100224);
  int* bsum    = (int*)alloc4(128);
  int* srcs    = (int*)alloc4(NE);
  unsigned short* xd   = (unsigned short*)alloc4((size_t)NN * 128 / 2);    // 25.6MB
  unsigned short* aggX = (unsigned short*)alloc4((size_t)MPAD * 128 / 2);  // 25.6MB
  unsigned short* td   = (unsigned short*)alloc4((size_t)MPAD * 128 / 2);  // 25.6MB
  unsigned short* Bt1h = (unsigned short*)alloc4(256 * 128 / 2);
  unsigned short* Bt1l = (unsigned short*)alloc4(256 * 128 / 2);
  unsigned short* Bt2h = (unsigned short*)alloc4(128 * 256 / 2);
  unsigned short* Bt2l = (unsigned short*)alloc4(128 * 256 / 2);
  float* pooled = (float*)alloc4((size_t)NG * F2);

  hipMemsetAsync(cnt, 0, 100224 * sizeof(int), stream);
  hipMemsetAsync(pooled, 0, (size_t)NG * F2 * sizeof(float), stream);

  // CSR build (shared by both conv layers); scan1 also emits dinv
  k_count<<<(NE + 255) / 256, 256, 0, stream>>>(dst, cnt);
  k_scan1<<<NB, SCAN_T, 0, stream>>>(cnt, off, bsum, dinv);
  k_scan2<<<1, 128, 0, stream>>>(bsum);
  k_scan3<<<(NN + 256) / 256, 256, 0, stream>>>(off, bsum, cur);
  k_place<<<(NE + 255) / 256, 256, 0, stream>>>(src, dst, cur, srcs);

  // weight prep (fp16 hi/lo, transposed, zero-padded) — single launch
  k_prepB2<<<256, 256, 0, stream>>>(W1, W2, Bt1h, Bt1l, Bt2h, Bt2l);

  // layer 1 input: fp16 table + wave-per-node gather -> aggX fp16
  k_prepx<<<NN, 128, 0, stream>>>(x, dinv, xd);
  k_gatherw<false><<<NN / 4, 256, 0, stream>>>(xd, dinv, off, srcs,
                                               nullptr, nullptr, aggX, nullptr);

  // fused conv1-GEMM + conv2-GEMM (h1 never leaves LDS) -> td fp16
  k_fused<<<MPAD / 64, 256, 0, stream>>>(aggX, Bt1h, Bt1l, Bt2h, Bt2l,
                                         b1, dinv, td);

  // layer 2 aggregation fused with relu(+b2) + per-graph max pool
  k_gatherw<true><<<NN / 4, 256, 0, stream>>>(td, dinv, off, srcs,
                                              b2, batch, nullptr, pooled);

  // head MLP
  k_mlp<<<NG, 64, 0, stream>>>(pooled, Wg, bg, Wf, bf, Wo, bo, (float*)d_out);
}

// Round 16
// 296.264 us; speedup vs baseline: 1.2539x; 1.0209x over previous
//
#include <hip/hip_runtime.h>
#include <hip/hip_bf16.h>
#include <hip/hip_fp16.h>

#define NN 100000
#define NG 256
#define NE 800000

constexpr int F0 = 114;   // x features
constexpr int F1 = 230;   // layer1 output features
constexpr int F2 = 115;   // layer2 output features
constexpr int MPAD = 100096;  // 1564 * 64

typedef _Float16 __attribute__((ext_vector_type(8))) f16x8;   // MFMA operand
typedef __attribute__((ext_vector_type(4))) float f32x4;      // MFMA acc
typedef __attribute__((ext_vector_type(8))) unsigned short u16x8;

__device__ __forceinline__ unsigned short f2h_bits(float x) {
  _Float16 h = (_Float16)x;
  return __builtin_bit_cast(unsigned short, h);
}
__device__ __forceinline__ float h_bits2f(unsigned short u) {
  return (float)__builtin_bit_cast(_Float16, u);
}

// barrier that fences LDS ops but does NOT drain in-flight global loads
// (__syncthreads would emit s_waitcnt vmcnt(0) and kill the B prefetch)
__device__ __forceinline__ void bar_nodrain() {
  asm volatile("s_waitcnt lgkmcnt(0)" ::: "memory");
  __builtin_amdgcn_s_barrier();
}

// ---------------- degree / CSR build ----------------

__global__ void k_count(const int* __restrict__ dst, int* __restrict__ cnt) {
  int e = blockIdx.x * blockDim.x + threadIdx.x;
  if (e < NE) atomicAdd(&cnt[dst[e]], 1);
}

constexpr int SCAN_T = 256;
constexpr int SCAN_E = 1024;
constexpr int NB = (NN + SCAN_E - 1) / SCAN_E;  // 98

// scan1 also emits dinv (fused former k_dinv)
__global__ void k_scan1(const int* __restrict__ cnt, int* __restrict__ off,
                        int* __restrict__ bsum, float* __restrict__ dinv) {
  __shared__ int s[SCAN_T];
  int b = blockIdx.x, t = threadIdx.x;
  int base = b * SCAN_E + t * 4;
  int v0 = 0, v1 = 0, v2 = 0, v3 = 0;
  if (base + 0 < NN) v0 = cnt[base + 0];
  if (base + 1 < NN) v1 = cnt[base + 1];
  if (base + 2 < NN) v2 = cnt[base + 2];
  if (base + 3 < NN) v3 = cnt[base + 3];
  if (base + 0 < NN) dinv[base + 0] = rsqrtf((float)v0 + 1.0f);
  if (base + 1 < NN) dinv[base + 1] = rsqrtf((float)v1 + 1.0f);
  if (base + 2 < NN) dinv[base + 2] = rsqrtf((float)v2 + 1.0f);
  if (base + 3 < NN) dinv[base + 3] = rsqrtf((float)v3 + 1.0f);
  int sum = v0 + v1 + v2 + v3;
  s[t] = sum;
  __syncthreads();
  for (int ofs = 1; ofs < SCAN_T; ofs <<= 1) {
    int x = (t >= ofs) ? s[t - ofs] : 0;
    __syncthreads();
    s[t] += x;
    __syncthreads();
  }
  int excl = s[t] - sum;
  if (base + 0 < NN) off[base + 0] = excl;
  if (base + 1 < NN) off[base + 1] = excl + v0;
  if (base + 2 < NN) off[base + 2] = excl + v0 + v1;
  if (base + 3 < NN) off[base + 3] = excl + v0 + v1 + v2;
  if (t == SCAN_T - 1) bsum[b] = s[t];
}

// scan3 with fused bsum-prefix (former k_scan2): each 256-node block sums
// bsum[0..seg) with one wave, then applies.
__global__ void k_scan3(int* __restrict__ off, const int* __restrict__ bsum,
                        int* __restrict__ cur) {
  __shared__ int pre;
  int b = blockIdx.x, t = threadIdx.x;
  int seg = b >> 2;  // (b*256)/SCAN_E
  if (t < 64) {
    int s = 0;
    for (int j = t; j < seg; j += 64) s += bsum[j];
#pragma unroll
    for (int o = 1; o < 64; o <<= 1) s += __shfl_xor(s, o);
    if (t == 0) pre = s;
  }
  __syncthreads();
  int i = b * 256 + t;
  if (i < NN) {
    int v = off[i] + pre;
    off[i] = v;
    cur[i] = v;
  }
  if (i == NN) off[NN] = NE;
}

__global__ void k_place(const int* __restrict__ src, const int* __restrict__ dst,
                        int* __restrict__ cur, int* __restrict__ srcs) {
  int e = blockIdx.x * blockDim.x + threadIdx.x;
  if (e >= NE) return;
  int p = atomicAdd(&cur[dst[e]], 1);
  srcs[p] = src[e];
}

// ---------------- fp16 tables ----------------

__global__ void k_prepx(const float* __restrict__ x, const float* __restrict__ dinv,
                        unsigned short* __restrict__ xd) {
  int n = blockIdx.x, f = threadIdx.x;  // 128 threads
  float v = (f < F0) ? x[(size_t)n * F0 + f] * dinv[n] : 0.0f;
  xd[(size_t)n * 128 + f] = f2h_bits(v);
}

// ---------------- wave-per-node gather: 16 edge slots/iter, 4 loads in flight

template <bool POOL>
__global__ __launch_bounds__(256) void k_gatherw(
    const unsigned short* __restrict__ tab, const float* __restrict__ dinv,
    const int* __restrict__ off, const int* __restrict__ srcs,
    const float* __restrict__ b2, const int* __restrict__ batch,
    unsigned short* __restrict__ outh, float* __restrict__ pooled) {
  __shared__ float smax[4][128];
  __shared__ int sg[4];
  int w = threadIdx.x >> 6, lane = threadIdx.x & 63;
  int n = blockIdx.x * 4 + w;
  int grp = lane >> 4, sub = lane & 15;
  int fb = sub * 8;

  float acc[8] = {0.f, 0.f, 0.f, 0.f, 0.f, 0.f, 0.f, 0.f};
  int j0 = off[n], j1 = off[n + 1];  // slots j0..j1, self at j1
  for (int base = j0; base <= j1; base += 16) {
    int row[4];
    u16x8 v[4];
    bool has[4];
#pragma unroll
    for (int c = 0; c < 4; ++c) {
      int je = base + c * 4 + grp;
      row[c] = (je < j1) ? srcs[je] : ((je == j1) ? n : -1);
      has[c] = row[c] >= 0;
    }
#pragma unroll
    for (int c = 0; c < 4; ++c)
      if (has[c]) v[c] = *(const u16x8*)&tab[(size_t)row[c] * 128 + fb];
#pragma unroll
    for (int c = 0; c < 4; ++c)
      if (has[c]) {
#pragma unroll
        for (int u = 0; u < 8; ++u) acc[u] += h_bits2f(v[c][u]);
      }
  }
#pragma unroll
  for (int u = 0; u < 8; ++u) {
    acc[u] += __shfl_xor(acc[u], 16);
    acc[u] += __shfl_xor(acc[u], 32);
  }
  float dn = dinv[n];

  if constexpr (!POOL) {
    if (grp == 0) {
      u16x8 o;
#pragma unroll
      for (int u = 0; u < 8; ++u) o[u] = f2h_bits(acc[u] * dn);
      *(u16x8*)&outh[(size_t)n * 128 + fb] = o;
    }
  } else {
    if (grp == 0) {
#pragma unroll
      for (int u = 0; u < 8; ++u) {
        int f = fb + u;
        float bb = (f < F2) ? b2[f] : 0.0f;
        smax[w][f] = fmaxf(acc[u] * dn + bb, 0.0f);
      }
      if (sub == 0) sg[w] = batch[n];
    }
    __syncthreads();
    int t = threadIdx.x;
    if (t < 128) {
      int g0 = sg[0];
      bool same = (sg[1] == g0) & (sg[2] == g0) & (sg[3] == g0);
      if (same) {
        float m = fmaxf(fmaxf(smax[0][t], smax[1][t]),
                        fmaxf(smax[2][t], smax[3][t]));
        if (t < F2 && m > 0.0f)
          atomicMax((int*)&pooled[g0 * F2 + t], __float_as_int(m));
      } else {
        for (int ww = 0; ww < 4; ++ww) {
          float m = smax[ww][t];
          if (t < F2 && m > 0.0f)
            atomicMax((int*)&pooled[sg[ww] * F2 + t], __float_as_int(m));
        }
      }
    }
  }
}

// ---------------- weight split+transpose prep (both matrices, one launch) ----

__global__ void k_prepB2(const float* __restrict__ W1, const float* __restrict__ W2,
                         unsigned short* __restrict__ B1h, unsigned short* __restrict__ B1l,
                         unsigned short* __restrict__ B2h, unsigned short* __restrict__ B2l) {
  int b = blockIdx.x, t = threadIdx.x;  // 256 threads
  if (b < 128) {  // B1: [256 n][128 k], two n-rows per block
    int n = b * 2 + (t >> 7), k = t & 127;
    float v = (k < F0 && n < F1) ? W1[(size_t)k * F1 + n] : 0.0f;
    unsigned short h = f2h_bits(v);
    unsigned short l = f2h_bits(v - h_bits2f(h));
    B1h[(size_t)n * 128 + k] = h;
    B1l[(size_t)n * 128 + k] = l;
  } else {        // B2: [128 n][256 k]
    int n = b - 128, k = t;
    float v = (k < F1 && n < F2) ? W2[(size_t)k * F2 + n] : 0.0f;
    unsigned short h = f2h_bits(v);
    unsigned short l = f2h_bits(v - h_bits2f(h));
    B2h[(size_t)n * 256 + k] = h;
    B2l[(size_t)n * 256 + k] = l;
  }
}

// ---------------- fused double GEMM v6: td = (relu(aggX@W1t^T+b1) @ W2t^T)*dinv
// v5 + barrier-nodrain: round barriers wait lgkmcnt(0) only (raw s_barrier),
// so the B register-prefetch issued in round r stays in flight across the
// barrier and completes under round r's MFMA (T4: never drain vmcnt at the
// barrier). Compiler still auto-waits vmcnt before the commit ds_write.
// LDS: h1B 32K + As 16K + Bs 2x16K = 80 KB -> 2 blocks/CU.
// Swizzle byte^=(row&7)<<4 (verified r13-r15; absmax must stay 4.88e-4).

__global__ __launch_bounds__(256) void k_fused(
    const unsigned short* __restrict__ A,                                   // [MPAD][128]
    const unsigned short* __restrict__ B1h, const unsigned short* __restrict__ B1l,  // [256][128]
    const unsigned short* __restrict__ B2h, const unsigned short* __restrict__ B2l,  // [128][256]
    const float* __restrict__ b1, const float* __restrict__ dscale,
    unsigned short* __restrict__ td) {                                      // [MPAD][128]
  __shared__ char lds[81920];
  char* h1B = lds;            // 32768 B: 64 rows x 512 B (256 fp16 cols, swizzled)
  char* AsB = lds + 32768;    // 16384 B: 64 rows x 256 B (128 fp16 k, swizzled)
  char* Bs0 = lds + 49152;    // 16384 B: 128 rows x 128 B (hi)
  char* Bs1 = lds + 65536;    // (lo)

  const int t = threadIdx.x;
  const int m0 = blockIdx.x * 64;
  const int lane = t & 63, w = t >> 6;
  const int r = lane & 15;
  const int kq = lane >> 4;          // k-quarter 0..3
  const int kb16 = kq * 16;          // byte offset of lane's 16B k-frag in 128B
  const int rq = kq * 4;
  const int wc = w * 32;             // wave's 32-col slice
  const int swr = (r & 7) << 4;      // MFMA-read swizzle
  const int arow = t >> 2, aseg = t & 3, aswz = (arow & 7) << 4;
  const int brow = t >> 1, bseg = t & 1, bswz = (brow & 7) << 4;

  // ---------- prologue: stage full A tile once; issue B(round 0) ----------
  {
    size_t ga = (size_t)(m0 + arow) * 128 + aseg * 32;
#pragma unroll
    for (int v = 0; v < 4; ++v) {
      u16x8 d = *(const u16x8*)&A[ga + v * 8];
      *(u16x8*)(AsB + arow * 256 + ((aseg * 64 + v * 16) ^ aswz)) = d;
    }
  }
  u16x8 ph[4], pl[4];
  {
    size_t gb = (size_t)brow * 128 + bseg * 32;  // B1, h=0, kc=0
#pragma unroll
    for (int v = 0; v < 4; ++v) {
      ph[v] = *(const u16x8*)&B1h[gb + v * 8];
      pl[v] = *(const u16x8*)&B1l[gb + v * 8];
    }
  }

  f32x4 acc1[4][2], acc2[4][2];
#pragma unroll
  for (int i = 0; i < 4; ++i)
#pragma unroll
    for (int j = 0; j < 2; ++j) {
      acc1[i][j] = (f32x4){0.f, 0.f, 0.f, 0.f};
      acc2[i][j] = (f32x4){0.f, 0.f, 0.f, 0.f};
    }

  // ---------- 8 pipelined rounds: 0..3 stage1 (h=rd>>1,kc=rd&1), 4..7 stage2
#pragma unroll
  for (int rd = 0; rd < 8; ++rd) {
    bar_nodrain();  // prev round's Bs readers done; rd=0: fences AsB writes
    // commit prefetched B to LDS (compiler auto-waits vmcnt for ph/pl)
#pragma unroll
    for (int v = 0; v < 4; ++v) {
      const int bo = (bseg * 64 + v * 16) ^ bswz;
      *(u16x8*)(Bs0 + brow * 128 + bo) = ph[v];
      *(u16x8*)(Bs1 + brow * 128 + bo) = pl[v];
    }
    // issue next round's B — stays in flight across the nodrain barrier,
    // completes under this round's MFMA phase
    if (rd < 7) {
      const int nr = rd + 1;
      const unsigned short* Gh = (nr < 4) ? B1h : B2h;
      const unsigned short* Gl = (nr < 4) ? B1l : B2l;
      const size_t gb = (nr < 4)
          ? (size_t)((nr >> 1) * 128 + brow) * 128 + (nr & 1) * 64 + bseg * 32
          : (size_t)brow * 256 + (nr - 4) * 64 + bseg * 32;
#pragma unroll
      for (int v = 0; v < 4; ++v) {
        ph[v] = *(const u16x8*)&Gh[gb + v * 8];
        pl[v] = *(const u16x8*)&Gl[gb + v * 8];
      }
    }
    bar_nodrain();  // Bs ready (lgkm only; prefetch loads NOT drained)

    if (rd < 4) {
      // ----- stage 1 MFMA: acc1 += A[:,kc*64..] @ B1-chunk -----
      const int kc = rd & 1;
#pragma unroll
      for (int ks = 0; ks < 2; ++ks) {
        f16x8 av[4], bh[2], bl[2];
#pragma unroll
        for (int i = 0; i < 4; ++i)
          av[i] = *(const f16x8*)(AsB + (i * 16 + r) * 256 +
                                  ((kc * 128 + ks * 64 + kb16) ^ swr));
#pragma unroll
        for (int j = 0; j < 2; ++j) {
          const int row = wc + j * 16 + r;
          const int bo = (ks * 64 + kb16) ^ swr;
          bh[j] = *(const f16x8*)(Bs0 + row * 128 + bo);
          bl[j] = *(const f16x8*)(Bs1 + row * 128 + bo);
        }
#pragma unroll
        for (int i = 0; i < 4; ++i)
#pragma unroll
          for (int j = 0; j < 2; ++j)
            acc1[i][j] = __builtin_amdgcn_mfma_f32_16x16x32_f16(av[i], bl[j], acc1[i][j], 0, 0, 0);
#pragma unroll
        for (int i = 0; i < 4; ++i)
#pragma unroll
          for (int j = 0; j < 2; ++j)
            acc1[i][j] = __builtin_amdgcn_mfma_f32_16x16x32_f16(av[i], bh[j], acc1[i][j], 0, 0, 0);
      }
      if (rd == 1 || rd == 3) {
        // bias+relu -> h1B (swizzled); read fenced by round-4 barrier
        // C/D layout: col = lane&15 (n), row = kq*4 + q (m)  [m89/m91]
        const int h = rd >> 1;
#pragma unroll
        for (int i = 0; i < 4; ++i)
#pragma unroll
          for (int j = 0; j < 2; ++j) {
            const int nl = wc + j * 16 + r;
            const int n = h * 128 + nl;
            const bool val = n < F1;
            const float bb = val ? b1[n] : 0.0f;
#pragma unroll
            for (int q = 0; q < 4; ++q) {
              const int ml = i * 16 + rq + q;
              const float v = val ? fmaxf(acc1[i][j][q] + bb, 0.0f) : 0.0f;
              *(unsigned short*)(h1B + ml * 512 + ((n * 2) ^ ((ml & 7) << 4))) = f2h_bits(v);
            }
          }
#pragma unroll
        for (int i = 0; i < 4; ++i)
#pragma unroll
          for (int j = 0; j < 2; ++j) acc1[i][j] = (f32x4){0.f, 0.f, 0.f, 0.f};
      }
    } else {
      // ----- stage 2 MFMA: acc2 += h1B[:,kc*64..] @ B2-chunk, K=256 -----
      const int kc = rd - 4;
#pragma unroll
      for (int ks = 0; ks < 2; ++ks) {
        f16x8 ah[4], bh[2], bl[2];
#pragma unroll
        for (int i = 0; i < 4; ++i) {
          const int row = i * 16 + r;
          ah[i] = *(const f16x8*)(h1B + row * 512 + ((kc * 128 + ks * 64 + kb16) ^ swr));
        }
#pragma unroll
        for (int j = 0; j < 2; ++j) {
          const int row = wc + j * 16 + r;
          const int bo = (ks * 64 + kb16) ^ swr;
          bh[j] = *(const f16x8*)(Bs0 + row * 128 + bo);
          bl[j] = *(const f16x8*)(Bs1 + row * 128 + bo);
        }
#pragma unroll
        for (int i = 0; i < 4; ++i)
#pragma unroll
          for (int j = 0; j < 2; ++j)
            acc2[i][j] = __builtin_amdgcn_mfma_f32_16x16x32_f16(ah[i], bl[j], acc2[i][j], 0, 0, 0);
#pragma unroll
        for (int i = 0; i < 4; ++i)
#pragma unroll
          for (int j = 0; j < 2; ++j)
            acc2[i][j] = __builtin_amdgcn_mfma_f32_16x16x32_f16(ah[i], bh[j], acc2[i][j], 0, 0, 0);
      }
    }
  }

  // epilogue: scale by dinv[m], stage fp16 tile into h1B (swizzled), store
  __syncthreads();  // all h1B reads done (full drain fine, once)
#pragma unroll
  for (int i = 0; i < 4; ++i)
#pragma unroll
    for (int j = 0; j < 2; ++j) {
      const int nl = wc + j * 16 + r;
#pragma unroll
      for (int q = 0; q < 4; ++q) {
        const int ml = i * 16 + rq + q;
        const float v = acc2[i][j][q] * dscale[m0 + ml];
        *(unsigned short*)(h1B + ml * 512 + ((nl * 2) ^ ((ml & 7) << 4))) = f2h_bits(v);
      }
    }
  __syncthreads();
  {
    const int row = t >> 2, seg = t & 3;
    const int swz = (row & 7) << 4;
    const size_t dst = (size_t)(m0 + row) * 128 + seg * 32;
#pragma unroll
    for (int v = 0; v < 4; ++v) {
      u16x8 d = *(const u16x8*)(h1B + row * 512 + ((seg * 64 + v * 16) ^ swz));
      *(u16x8*)&td[dst + v * 8] = d;
    }
  }
}

// ---------------- tiny MLP head: 115 -> 64 -> 32 -> 1 ----------------

__global__ void k_mlp(const float* __restrict__ pooled,
                      const float* __restrict__ Wg, const float* __restrict__ bg,
                      const float* __restrict__ Wf, const float* __restrict__ bf,
                      const float* __restrict__ Wo, const float* __restrict__ bo,
                      float* __restrict__ out) {
  __shared__ float sp[F2];
  __shared__ float sg[64];
  __shared__ float sf[32];
  int g = blockIdx.x, t = threadIdx.x;
  for (int f = t; f < F2; f += 64) sp[f] = pooled[g * F2 + f];
  __syncthreads();
  float a = bg[t];
  for (int k = 0; k < F2; ++k) a += sp[k] * Wg[k * 64 + t];
  sg[t] = fmaxf(a, 0.0f);
  __syncthreads();
  if (t < 32) {
    float c = bf[t];
    for (int k = 0; k < 64; ++k) c += sg[k] * Wf[k * 32 + t];
    sf[t] = fmaxf(c, 0.0f);
  }
  __syncthreads();
  if (t == 0) {
    float c = bo[0];
    for (int k = 0; k < 32; ++k) c += sf[k] * Wo[k];
    out[g] = c;
  }
}

// ---------------- launch ----------------

extern "C" void kernel_launch(void* const* d_in, const int* in_sizes, int n_in,
                              void* d_out, int out_size, void* d_ws, size_t ws_size,
                              hipStream_t stream) {
  const float* x  = (const float*)d_in[0];
  const int* ei   = (const int*)d_in[1];
  const int* batch = (const int*)d_in[2];
  const float* W1 = (const float*)d_in[3];
  const float* b1 = (const float*)d_in[4];
  const float* W2 = (const float*)d_in[5];
  const float* b2 = (const float*)d_in[6];
  const float* Wg = (const float*)d_in[7];
  const float* bg = (const float*)d_in[8];
  const float* Wf = (const float*)d_in[9];
  const float* bf = (const float*)d_in[10];
  const float* Wo = (const float*)d_in[11];
  const float* bo = (const float*)d_in[12];
  const int* src = ei;
  const int* dst = ei + NE;

  char* p = (char*)d_ws;
  auto alloc4 = [&](size_t units) { void* r = p; p += units * 4; return r; };
  float* dinv  = (float*)alloc4(100224);
  int* cnt     = (int*)alloc4(100224);
  int* off     = (int*)alloc4(100352);
  int* cur     = (int*)alloc4(100224);
  int* bsum    = (int*)alloc4(128);
  int* srcs    = (int*)alloc4(NE);
  unsigned short* xd   = (unsigned short*)alloc4((size_t)NN * 128 / 2);    // 25.6MB
  unsigned short* aggX = (unsigned short*)alloc4((size_t)MPAD * 128 / 2);  // 25.6MB
  unsigned short* td   = (unsigned short*)alloc4((size_t)MPAD * 128 / 2);  // 25.6MB
  unsigned short* Bt1h = (unsigned short*)alloc4(256 * 128 / 2);
  unsigned short* Bt1l = (unsigned short*)alloc4(256 * 128 / 2);
  unsigned short* Bt2h = (unsigned short*)alloc4(128 * 256 / 2);
  unsigned short* Bt2l = (unsigned short*)alloc4(128 * 256 / 2);
  float* pooled = (float*)alloc4((size_t)NG * F2);

  hipMemsetAsync(cnt, 0, 100224 * sizeof(int), stream);
  hipMemsetAsync(pooled, 0, (size_t)NG * F2 * sizeof(float), stream);

  // CSR build (shared by both conv layers); scan1 also emits dinv
  k_count<<<(NE + 255) / 256, 256, 0, stream>>>(dst, cnt);
  k_scan1<<<NB, SCAN_T, 0, stream>>>(cnt, off, bsum, dinv);
  k_scan3<<<(NN + 256) / 256, 256, 0, stream>>>(off, bsum, cur);
  k_place<<<(NE + 255) / 256, 256, 0, stream>>>(src, dst, cur, srcs);

  // weight prep (fp16 hi/lo, transposed, zero-padded) — single launch
  k_prepB2<<<256, 256, 0, stream>>>(W1, W2, Bt1h, Bt1l, Bt2h, Bt2l);

  // layer 1 input: fp16 table + wave-per-node gather -> aggX fp16
  k_prepx<<<NN, 128, 0, stream>>>(x, dinv, xd);
  k_gatherw<false><<<NN / 4, 256, 0, stream>>>(xd, dinv, off, srcs,
                                               nullptr, nullptr, aggX, nullptr);

  // fused conv1-GEMM + conv2-GEMM (h1 never leaves LDS) -> td fp16
  k_fused<<<MPAD / 64, 256, 0, stream>>>(aggX, Bt1h, Bt1l, Bt2h, Bt2l,
                                         b1, dinv, td);

  // layer 2 aggregation fused with relu(+b2) + per-graph max pool
  k_gatherw<true><<<NN / 4, 256, 0, stream>>>(td, dinv, off, srcs,
                                              b2, batch, nullptr, pooled);

  // head MLP
  k_mlp<<<NG, 64, 0, stream>>>(pooled, Wg, bg, Wf, bf, Wo, bo, (float*)d_out);
}

// Round 17
// 291.842 us; speedup vs baseline: 1.2729x; 1.0152x over previous
//
#include <hip/hip_runtime.h>
#include <hip/hip_bf16.h>
#include <hip/hip_fp16.h>

#define NN 100000
#define NG 256
#define NE 800000

constexpr int F0 = 114;   // x features
constexpr int F1 = 230;   // layer1 output features
constexpr int F2 = 115;   // layer2 output features
constexpr int MPAD = 100096;  // 1564 * 64

typedef _Float16 __attribute__((ext_vector_type(8))) f16x8;   // MFMA operand
typedef __attribute__((ext_vector_type(4))) float f32x4;      // MFMA acc
typedef __attribute__((ext_vector_type(8))) unsigned short u16x8;

__device__ __forceinline__ unsigned short f2h_bits(float x) {
  _Float16 h = (_Float16)x;
  return __builtin_bit_cast(unsigned short, h);
}
__device__ __forceinline__ float h_bits2f(unsigned short u) {
  return (float)__builtin_bit_cast(_Float16, u);
}

// barrier that fences LDS ops but does NOT drain in-flight global loads
__device__ __forceinline__ void bar_nodrain() {
  asm volatile("s_waitcnt lgkmcnt(0)" ::: "memory");
  __builtin_amdgcn_s_barrier();
}

// ---------------- degree / CSR build ----------------

__global__ void k_count(const int* __restrict__ dst, int* __restrict__ cnt) {
  int e = blockIdx.x * blockDim.x + threadIdx.x;
  if (e < NE) atomicAdd(&cnt[dst[e]], 1);
}

constexpr int SCAN_T = 256;
constexpr int SCAN_E = 1024;
constexpr int NB = (NN + SCAN_E - 1) / SCAN_E;  // 98

// scan1 also emits dinv (fused former k_dinv)
__global__ void k_scan1(const int* __restrict__ cnt, int* __restrict__ off,
                        int* __restrict__ bsum, float* __restrict__ dinv) {
  __shared__ int s[SCAN_T];
  int b = blockIdx.x, t = threadIdx.x;
  int base = b * SCAN_E + t * 4;
  int v0 = 0, v1 = 0, v2 = 0, v3 = 0;
  if (base + 0 < NN) v0 = cnt[base + 0];
  if (base + 1 < NN) v1 = cnt[base + 1];
  if (base + 2 < NN) v2 = cnt[base + 2];
  if (base + 3 < NN) v3 = cnt[base + 3];
  if (base + 0 < NN) dinv[base + 0] = rsqrtf((float)v0 + 1.0f);
  if (base + 1 < NN) dinv[base + 1] = rsqrtf((float)v1 + 1.0f);
  if (base + 2 < NN) dinv[base + 2] = rsqrtf((float)v2 + 1.0f);
  if (base + 3 < NN) dinv[base + 3] = rsqrtf((float)v3 + 1.0f);
  int sum = v0 + v1 + v2 + v3;
  s[t] = sum;
  __syncthreads();
  for (int ofs = 1; ofs < SCAN_T; ofs <<= 1) {
    int x = (t >= ofs) ? s[t - ofs] : 0;
    __syncthreads();
    s[t] += x;
    __syncthreads();
  }
  int excl = s[t] - sum;
  if (base + 0 < NN) off[base + 0] = excl;
  if (base + 1 < NN) off[base + 1] = excl + v0;
  if (base + 2 < NN) off[base + 2] = excl + v0 + v1;
  if (base + 3 < NN) off[base + 3] = excl + v0 + v1 + v2;
  if (t == SCAN_T - 1) bsum[b] = s[t];
}

// scan3 with fused bsum-prefix: each 256-node block sums bsum[0..seg)
__global__ void k_scan3(int* __restrict__ off, const int* __restrict__ bsum,
                        int* __restrict__ cur) {
  __shared__ int pre;
  int b = blockIdx.x, t = threadIdx.x;
  int seg = b >> 2;  // (b*256)/SCAN_E
  if (t < 64) {
    int s = 0;
    for (int j = t; j < seg; j += 64) s += bsum[j];
#pragma unroll
    for (int o = 1; o < 64; o <<= 1) s += __shfl_xor(s, o);
    if (t == 0) pre = s;
  }
  __syncthreads();
  int i = b * 256 + t;
  if (i < NN) {
    int v = off[i] + pre;
    off[i] = v;
    cur[i] = v;
  }
  if (i == NN) off[NN] = NE;
}

// ---------------- fat kernel: place ∥ prepx ∥ prepB2 ∥ pooled-zero ----------
// Independent post-scan work merged into one launch: atomic-latency-bound
// place blocks overlap BW-bound prepx blocks on the machine.

constexpr int FB_PLACE = (NE + 255) / 256;      // 3125
constexpr int FB_PREPX = NN / 2;                // 50000 (2 nodes/block)
constexpr int FB_PREPB = 256;
constexpr int FB_POOL  = (NG * F2 + 255) / 256; // 115

__global__ __launch_bounds__(256) void k_fatB(
    const int* __restrict__ src, const int* __restrict__ dst,
    int* __restrict__ cur, int* __restrict__ srcs,
    const float* __restrict__ x, const float* __restrict__ dinv,
    unsigned short* __restrict__ xd,
    const float* __restrict__ W1, const float* __restrict__ W2,
    unsigned short* __restrict__ B1h, unsigned short* __restrict__ B1l,
    unsigned short* __restrict__ B2h, unsigned short* __restrict__ B2l,
    float* __restrict__ pooled) {
  int b = blockIdx.x, t = threadIdx.x;
  if (b < FB_PLACE) {
    int e = b * 256 + t;
    if (e < NE) {
      int p = atomicAdd(&cur[dst[e]], 1);
      srcs[p] = src[e];
    }
  } else if (b < FB_PLACE + FB_PREPX) {
    int bb = b - FB_PLACE;
    int n = bb * 2 + (t >> 7);
    int f = t & 127;
    float v = (f < F0) ? x[(size_t)n * F0 + f] * dinv[n] : 0.0f;
    xd[(size_t)n * 128 + f] = f2h_bits(v);
  } else if (b < FB_PLACE + FB_PREPX + FB_PREPB) {
    int bb = b - (FB_PLACE + FB_PREPX);
    if (bb < 128) {  // B1: [256 n][128 k], two n-rows per block
      int n = bb * 2 + (t >> 7), k = t & 127;
      float v = (k < F0 && n < F1) ? W1[(size_t)k * F1 + n] : 0.0f;
      unsigned short h = f2h_bits(v);
      unsigned short l = f2h_bits(v - h_bits2f(h));
      B1h[(size_t)n * 128 + k] = h;
      B1l[(size_t)n * 128 + k] = l;
    } else {         // B2: [128 n][256 k]
      int n = bb - 128, k = t;
      float v = (k < F1 && n < F2) ? W2[(size_t)k * F2 + n] : 0.0f;
      unsigned short h = f2h_bits(v);
      unsigned short l = f2h_bits(v - h_bits2f(h));
      B2h[(size_t)n * 256 + k] = h;
      B2l[(size_t)n * 256 + k] = l;
    }
  } else {
    int bb = b - (FB_PLACE + FB_PREPX + FB_PREPB);
    int i = bb * 256 + t;
    if (i < NG * F2) pooled[i] = 0.0f;
  }
}

// ---------------- wave-per-node gather: 16 edge slots/iter, 4 loads in flight

template <bool POOL>
__global__ __launch_bounds__(256) void k_gatherw(
    const unsigned short* __restrict__ tab, const float* __restrict__ dinv,
    const int* __restrict__ off, const int* __restrict__ srcs,
    const float* __restrict__ b2, const int* __restrict__ batch,
    unsigned short* __restrict__ outh, float* __restrict__ pooled) {
  __shared__ float smax[4][128];
  __shared__ int sg[4];
  int w = threadIdx.x >> 6, lane = threadIdx.x & 63;
  int n = blockIdx.x * 4 + w;
  int grp = lane >> 4, sub = lane & 15;
  int fb = sub * 8;

  float acc[8] = {0.f, 0.f, 0.f, 0.f, 0.f, 0.f, 0.f, 0.f};
  int j0 = off[n], j1 = off[n + 1];  // slots j0..j1, self at j1
  for (int base = j0; base <= j1; base += 16) {
    int row[4];
    u16x8 v[4];
    bool has[4];
#pragma unroll
    for (int c = 0; c < 4; ++c) {
      int je = base + c * 4 + grp;
      row[c] = (je < j1) ? srcs[je] : ((je == j1) ? n : -1);
      has[c] = row[c] >= 0;
    }
#pragma unroll
    for (int c = 0; c < 4; ++c)
      if (has[c]) v[c] = *(const u16x8*)&tab[(size_t)row[c] * 128 + fb];
#pragma unroll
    for (int c = 0; c < 4; ++c)
      if (has[c]) {
#pragma unroll
        for (int u = 0; u < 8; ++u) acc[u] += h_bits2f(v[c][u]);
      }
  }
#pragma unroll
  for (int u = 0; u < 8; ++u) {
    acc[u] += __shfl_xor(acc[u], 16);
    acc[u] += __shfl_xor(acc[u], 32);
  }
  float dn = dinv[n];

  if constexpr (!POOL) {
    if (grp == 0) {
      u16x8 o;
#pragma unroll
      for (int u = 0; u < 8; ++u) o[u] = f2h_bits(acc[u] * dn);
      *(u16x8*)&outh[(size_t)n * 128 + fb] = o;
    }
  } else {
    if (grp == 0) {
#pragma unroll
      for (int u = 0; u < 8; ++u) {
        int f = fb + u;
        float bb = (f < F2) ? b2[f] : 0.0f;
        smax[w][f] = fmaxf(acc[u] * dn + bb, 0.0f);
      }
      if (sub == 0) sg[w] = batch[n];
    }
    __syncthreads();
    int t = threadIdx.x;
    if (t < 128) {
      int g0 = sg[0];
      bool same = (sg[1] == g0) & (sg[2] == g0) & (sg[3] == g0);
      if (same) {
        float m = fmaxf(fmaxf(smax[0][t], smax[1][t]),
                        fmaxf(smax[2][t], smax[3][t]));
        if (t < F2 && m > 0.0f)
          atomicMax((int*)&pooled[g0 * F2 + t], __float_as_int(m));
      } else {
        for (int ww = 0; ww < 4; ++ww) {
          float m = smax[ww][t];
          if (t < F2 && m > 0.0f)
            atomicMax((int*)&pooled[sg[ww] * F2 + t], __float_as_int(m));
        }
      }
    }
  }
}

// ---------------- fused double GEMM v7: v6 + T5 setprio around MFMA --------
// LDS: h1B 32K + As 16K + Bs 2x16K = 80 KB -> 2 blocks/CU.
// Swizzle byte^=(row&7)<<4 (verified r13-r16; absmax must stay 4.88e-4).

__global__ __launch_bounds__(256) void k_fused(
    const unsigned short* __restrict__ A,                                   // [MPAD][128]
    const unsigned short* __restrict__ B1h, const unsigned short* __restrict__ B1l,  // [256][128]
    const unsigned short* __restrict__ B2h, const unsigned short* __restrict__ B2l,  // [128][256]
    const float* __restrict__ b1, const float* __restrict__ dscale,
    unsigned short* __restrict__ td) {                                      // [MPAD][128]
  __shared__ char lds[81920];
  char* h1B = lds;            // 32768 B: 64 rows x 512 B (256 fp16 cols, swizzled)
  char* AsB = lds + 32768;    // 16384 B: 64 rows x 256 B (128 fp16 k, swizzled)
  char* Bs0 = lds + 49152;    // 16384 B: 128 rows x 128 B (hi)
  char* Bs1 = lds + 65536;    // (lo)

  const int t = threadIdx.x;
  const int m0 = blockIdx.x * 64;
  const int lane = t & 63, w = t >> 6;
  const int r = lane & 15;
  const int kq = lane >> 4;
  const int kb16 = kq * 16;
  const int rq = kq * 4;
  const int wc = w * 32;
  const int swr = (r & 7) << 4;
  const int arow = t >> 2, aseg = t & 3, aswz = (arow & 7) << 4;
  const int brow = t >> 1, bseg = t & 1, bswz = (brow & 7) << 4;

  // ---------- prologue: stage full A tile once; issue B(round 0) ----------
  {
    size_t ga = (size_t)(m0 + arow) * 128 + aseg * 32;
#pragma unroll
    for (int v = 0; v < 4; ++v) {
      u16x8 d = *(const u16x8*)&A[ga + v * 8];
      *(u16x8*)(AsB + arow * 256 + ((aseg * 64 + v * 16) ^ aswz)) = d;
    }
  }
  u16x8 ph[4], pl[4];
  {
    size_t gb = (size_t)brow * 128 + bseg * 32;  // B1, h=0, kc=0
#pragma unroll
    for (int v = 0; v < 4; ++v) {
      ph[v] = *(const u16x8*)&B1h[gb + v * 8];
      pl[v] = *(const u16x8*)&B1l[gb + v * 8];
    }
  }

  f32x4 acc1[4][2], acc2[4][2];
#pragma unroll
  for (int i = 0; i < 4; ++i)
#pragma unroll
    for (int j = 0; j < 2; ++j) {
      acc1[i][j] = (f32x4){0.f, 0.f, 0.f, 0.f};
      acc2[i][j] = (f32x4){0.f, 0.f, 0.f, 0.f};
    }

  // ---------- 8 pipelined rounds: 0..3 stage1 (h=rd>>1,kc=rd&1), 4..7 stage2
#pragma unroll
  for (int rd = 0; rd < 8; ++rd) {
    bar_nodrain();  // prev round's Bs readers done; rd=0: fences AsB writes
#pragma unroll
    for (int v = 0; v < 4; ++v) {
      const int bo = (bseg * 64 + v * 16) ^ bswz;
      *(u16x8*)(Bs0 + brow * 128 + bo) = ph[v];
      *(u16x8*)(Bs1 + brow * 128 + bo) = pl[v];
    }
    if (rd < 7) {
      const int nr = rd + 1;
      const unsigned short* Gh = (nr < 4) ? B1h : B2h;
      const unsigned short* Gl = (nr < 4) ? B1l : B2l;
      const size_t gb = (nr < 4)
          ? (size_t)((nr >> 1) * 128 + brow) * 128 + (nr & 1) * 64 + bseg * 32
          : (size_t)brow * 256 + (nr - 4) * 64 + bseg * 32;
#pragma unroll
      for (int v = 0; v < 4; ++v) {
        ph[v] = *(const u16x8*)&Gh[gb + v * 8];
        pl[v] = *(const u16x8*)&Gl[gb + v * 8];
      }
    }
    bar_nodrain();  // Bs ready (lgkm only; prefetch loads NOT drained)

    if (rd < 4) {
      const int kc = rd & 1;
#pragma unroll
      for (int ks = 0; ks < 2; ++ks) {
        f16x8 av[4], bh[2], bl[2];
#pragma unroll
        for (int i = 0; i < 4; ++i)
          av[i] = *(const f16x8*)(AsB + (i * 16 + r) * 256 +
                                  ((kc * 128 + ks * 64 + kb16) ^ swr));
#pragma unroll
        for (int j = 0; j < 2; ++j) {
          const int row = wc + j * 16 + r;
          const int bo = (ks * 64 + kb16) ^ swr;
          bh[j] = *(const f16x8*)(Bs0 + row * 128 + bo);
          bl[j] = *(const f16x8*)(Bs1 + row * 128 + bo);
        }
        __builtin_amdgcn_s_setprio(1);  // T5: favor MFMA cluster
#pragma unroll
        for (int i = 0; i < 4; ++i)
#pragma unroll
          for (int j = 0; j < 2; ++j)
            acc1[i][j] = __builtin_amdgcn_mfma_f32_16x16x32_f16(av[i], bl[j], acc1[i][j], 0, 0, 0);
#pragma unroll
        for (int i = 0; i < 4; ++i)
#pragma unroll
          for (int j = 0; j < 2; ++j)
            acc1[i][j] = __builtin_amdgcn_mfma_f32_16x16x32_f16(av[i], bh[j], acc1[i][j], 0, 0, 0);
        __builtin_amdgcn_s_setprio(0);
      }
      if (rd == 1 || rd == 3) {
        // bias+relu -> h1B; C/D layout: col=lane&15, row=kq*4+q  [m89/m91]
        const int h = rd >> 1;
#pragma unroll
        for (int i = 0; i < 4; ++i)
#pragma unroll
          for (int j = 0; j < 2; ++j) {
            const int nl = wc + j * 16 + r;
            const int n = h * 128 + nl;
            const bool val = n < F1;
            const float bb = val ? b1[n] : 0.0f;
#pragma unroll
            for (int q = 0; q < 4; ++q) {
              const int ml = i * 16 + rq + q;
              const float v = val ? fmaxf(acc1[i][j][q] + bb, 0.0f) : 0.0f;
              *(unsigned short*)(h1B + ml * 512 + ((n * 2) ^ ((ml & 7) << 4))) = f2h_bits(v);
            }
          }
#pragma unroll
        for (int i = 0; i < 4; ++i)
#pragma unroll
          for (int j = 0; j < 2; ++j) acc1[i][j] = (f32x4){0.f, 0.f, 0.f, 0.f};
      }
    } else {
      const int kc = rd - 4;
#pragma unroll
      for (int ks = 0; ks < 2; ++ks) {
        f16x8 ah[4], bh[2], bl[2];
#pragma unroll
        for (int i = 0; i < 4; ++i) {
          const int row = i * 16 + r;
          ah[i] = *(const f16x8*)(h1B + row * 512 + ((kc * 128 + ks * 64 + kb16) ^ swr));
        }
#pragma unroll
        for (int j = 0; j < 2; ++j) {
          const int row = wc + j * 16 + r;
          const int bo = (ks * 64 + kb16) ^ swr;
          bh[j] = *(const f16x8*)(Bs0 + row * 128 + bo);
          bl[j] = *(const f16x8*)(Bs1 + row * 128 + bo);
        }
        __builtin_amdgcn_s_setprio(1);
#pragma unroll
        for (int i = 0; i < 4; ++i)
#pragma unroll
          for (int j = 0; j < 2; ++j)
            acc2[i][j] = __builtin_amdgcn_mfma_f32_16x16x32_f16(ah[i], bl[j], acc2[i][j], 0, 0, 0);
#pragma unroll
        for (int i = 0; i < 4; ++i)
#pragma unroll
          for (int j = 0; j < 2; ++j)
            acc2[i][j] = __builtin_amdgcn_mfma_f32_16x16x32_f16(ah[i], bh[j], acc2[i][j], 0, 0, 0);
        __builtin_amdgcn_s_setprio(0);
      }
    }
  }

  // epilogue: scale by dinv[m], stage fp16 tile into h1B (swizzled), store
  __syncthreads();
#pragma unroll
  for (int i = 0; i < 4; ++i)
#pragma unroll
    for (int j = 0; j < 2; ++j) {
      const int nl = wc + j * 16 + r;
#pragma unroll
      for (int q = 0; q < 4; ++q) {
        const int ml = i * 16 + rq + q;
        const float v = acc2[i][j][q] * dscale[m0 + ml];
        *(unsigned short*)(h1B + ml * 512 + ((nl * 2) ^ ((ml & 7) << 4))) = f2h_bits(v);
      }
    }
  __syncthreads();
  {
    const int row = t >> 2, seg = t & 3;
    const int swz = (row & 7) << 4;
    const size_t dst = (size_t)(m0 + row) * 128 + seg * 32;
#pragma unroll
    for (int v = 0; v < 4; ++v) {
      u16x8 d = *(const u16x8*)(h1B + row * 512 + ((seg * 64 + v * 16) ^ swz));
      *(u16x8*)&td[dst + v * 8] = d;
    }
  }
}

// ---------------- tiny MLP head: 115 -> 64 -> 32 -> 1 ----------------

__global__ void k_mlp(const float* __restrict__ pooled,
                      const float* __restrict__ Wg, const float* __restrict__ bg,
                      const float* __restrict__ Wf, const float* __restrict__ bf,
                      const float* __restrict__ Wo, const float* __restrict__ bo,
                      float* __restrict__ out) {
  __shared__ float sp[F2];
  __shared__ float sg[64];
  __shared__ float sf[32];
  int g = blockIdx.x, t = threadIdx.x;
  for (int f = t; f < F2; f += 64) sp[f] = pooled[g * F2 + f];
  __syncthreads();
  float a = bg[t];
  for (int k = 0; k < F2; ++k) a += sp[k] * Wg[k * 64 + t];
  sg[t] = fmaxf(a, 0.0f);
  __syncthreads();
  if (t < 32) {
    float c = bf[t];
    for (int k = 0; k < 64; ++k) c += sg[k] * Wf[k * 32 + t];
    sf[t] = fmaxf(c, 0.0f);
  }
  __syncthreads();
  if (t == 0) {
    float c = bo[0];
    for (int k = 0; k < 32; ++k) c += sf[k] * Wo[k];
    out[g] = c;
  }
}

// ---------------- launch ----------------

extern "C" void kernel_launch(void* const* d_in, const int* in_sizes, int n_in,
                              void* d_out, int out_size, void* d_ws, size_t ws_size,
                              hipStream_t stream) {
  const float* x  = (const float*)d_in[0];
  const int* ei   = (const int*)d_in[1];
  const int* batch = (const int*)d_in[2];
  const float* W1 = (const float*)d_in[3];
  const float* b1 = (const float*)d_in[4];
  const float* W2 = (const float*)d_in[5];
  const float* b2 = (const float*)d_in[6];
  const float* Wg = (const float*)d_in[7];
  const float* bg = (const float*)d_in[8];
  const float* Wf = (const float*)d_in[9];
  const float* bf = (const float*)d_in[10];
  const float* Wo = (const float*)d_in[11];
  const float* bo = (const float*)d_in[12];
  const int* src = ei;
  const int* dst = ei + NE;

  char* p = (char*)d_ws;
  auto alloc4 = [&](size_t units) { void* r = p; p += units * 4; return r; };
  float* dinv  = (float*)alloc4(100224);
  int* cnt     = (int*)alloc4(100224);
  int* off     = (int*)alloc4(100352);
  int* cur     = (int*)alloc4(100224);
  int* bsum    = (int*)alloc4(128);
  int* srcs    = (int*)alloc4(NE);
  unsigned short* xd   = (unsigned short*)alloc4((size_t)NN * 128 / 2);    // 25.6MB
  unsigned short* aggX = (unsigned short*)alloc4((size_t)MPAD * 128 / 2);  // 25.6MB
  unsigned short* td   = (unsigned short*)alloc4((size_t)MPAD * 128 / 2);  // 25.6MB
  unsigned short* Bt1h = (unsigned short*)alloc4(256 * 128 / 2);
  unsigned short* Bt1l = (unsigned short*)alloc4(256 * 128 / 2);
  unsigned short* Bt2h = (unsigned short*)alloc4(128 * 256 / 2);
  unsigned short* Bt2l = (unsigned short*)alloc4(128 * 256 / 2);
  float* pooled = (float*)alloc4((size_t)NG * F2);

  hipMemsetAsync(cnt, 0, 100224 * sizeof(int), stream);

  // CSR count + scan (scan1 also emits dinv)
  k_count<<<(NE + 255) / 256, 256, 0, stream>>>(dst, cnt);
  k_scan1<<<NB, SCAN_T, 0, stream>>>(cnt, off, bsum, dinv);
  k_scan3<<<(NN + 256) / 256, 256, 0, stream>>>(off, bsum, cur);

  // fat: place ∥ prepx ∥ prepB2 ∥ pooled-zero (independent, one launch)
  k_fatB<<<FB_PLACE + FB_PREPX + FB_PREPB + FB_POOL, 256, 0, stream>>>(
      src, dst, cur, srcs, x, dinv, xd, W1, W2,
      Bt1h, Bt1l, Bt2h, Bt2l, pooled);

  // layer 1 aggregation -> aggX fp16
  k_gatherw<false><<<NN / 4, 256, 0, stream>>>(xd, dinv, off, srcs,
                                               nullptr, nullptr, aggX, nullptr);

  // fused conv1-GEMM + conv2-GEMM (h1 never leaves LDS) -> td fp16
  k_fused<<<MPAD / 64, 256, 0, stream>>>(aggX, Bt1h, Bt1l, Bt2h, Bt2l,
                                         b1, dinv, td);

  // layer 2 aggregation fused with relu(+b2) + per-graph max pool
  k_gatherw<true><<<NN / 4, 256, 0, stream>>>(td, dinv, off, srcs,
                                              b2, batch, nullptr, pooled);

  // head MLP
  k_mlp<<<NG, 64, 0, stream>>>(pooled, Wg, bg, Wf, bf, Wo, bo, (float*)d_out);
}

// Round 18
// 267.754 us; speedup vs baseline: 1.3874x; 1.0900x over previous
//
#include <hip/hip_runtime.h>
#include <hip/hip_bf16.h>
#include <hip/hip_fp16.h>

#define NN 100000
#define NG 256
#define NE 800000

constexpr int F0 = 114;   // x features
constexpr int F1 = 230;   // layer1 output features
constexpr int F2 = 115;   // layer2 output features
constexpr int MPAD = 100096;  // 1564 * 64

typedef _Float16 __attribute__((ext_vector_type(8))) f16x8;   // MFMA operand
typedef __attribute__((ext_vector_type(4))) float f32x4;      // MFMA acc
typedef __attribute__((ext_vector_type(8))) unsigned short u16x8;

__device__ __forceinline__ unsigned short f2h_bits(float x) {
  _Float16 h = (_Float16)x;
  return __builtin_bit_cast(unsigned short, h);
}
__device__ __forceinline__ float h_bits2f(unsigned short u) {
  return (float)__builtin_bit_cast(_Float16, u);
}

// barrier that fences LDS ops but does NOT drain in-flight global loads
__device__ __forceinline__ void bar_nodrain() {
  asm volatile("s_waitcnt lgkmcnt(0)" ::: "memory");
  __builtin_amdgcn_s_barrier();
}

// ---------------- degree / CSR build ----------------

__global__ void k_count(const int* __restrict__ dst, int* __restrict__ cnt) {
  int e = blockIdx.x * blockDim.x + threadIdx.x;
  if (e < NE) atomicAdd(&cnt[dst[e]], 1);
}

constexpr int SCAN_T = 256;
constexpr int SCAN_E = 1024;
constexpr int NB = (NN + SCAN_E - 1) / SCAN_E;  // 98

// scan1 also emits dinv (fused former k_dinv)
__global__ void k_scan1(const int* __restrict__ cnt, int* __restrict__ off,
                        int* __restrict__ bsum, float* __restrict__ dinv) {
  __shared__ int s[SCAN_T];
  int b = blockIdx.x, t = threadIdx.x;
  int base = b * SCAN_E + t * 4;
  int v0 = 0, v1 = 0, v2 = 0, v3 = 0;
  if (base + 0 < NN) v0 = cnt[base + 0];
  if (base + 1 < NN) v1 = cnt[base + 1];
  if (base + 2 < NN) v2 = cnt[base + 2];
  if (base + 3 < NN) v3 = cnt[base + 3];
  if (base + 0 < NN) dinv[base + 0] = rsqrtf((float)v0 + 1.0f);
  if (base + 1 < NN) dinv[base + 1] = rsqrtf((float)v1 + 1.0f);
  if (base + 2 < NN) dinv[base + 2] = rsqrtf((float)v2 + 1.0f);
  if (base + 3 < NN) dinv[base + 3] = rsqrtf((float)v3 + 1.0f);
  int sum = v0 + v1 + v2 + v3;
  s[t] = sum;
  __syncthreads();
  for (int ofs = 1; ofs < SCAN_T; ofs <<= 1) {
    int x = (t >= ofs) ? s[t - ofs] : 0;
    __syncthreads();
    s[t] += x;
    __syncthreads();
  }
  int excl = s[t] - sum;
  if (base + 0 < NN) off[base + 0] = excl;
  if (base + 1 < NN) off[base + 1] = excl + v0;
  if (base + 2 < NN) off[base + 2] = excl + v0 + v1;
  if (base + 3 < NN) off[base + 3] = excl + v0 + v1 + v2;
  if (t == SCAN_T - 1) bsum[b] = s[t];
}

// scan3 with fused bsum-prefix: each 256-node block sums bsum[0..seg)
__global__ void k_scan3(int* __restrict__ off, const int* __restrict__ bsum,
                        int* __restrict__ cur) {
  __shared__ int pre;
  int b = blockIdx.x, t = threadIdx.x;
  int seg = b >> 2;  // (b*256)/SCAN_E
  if (t < 64) {
    int s = 0;
    for (int j = t; j < seg; j += 64) s += bsum[j];
#pragma unroll
    for (int o = 1; o < 64; o <<= 1) s += __shfl_xor(s, o);
    if (t == 0) pre = s;
  }
  __syncthreads();
  int i = b * 256 + t;
  if (i < NN) {
    int v = off[i] + pre;
    off[i] = v;
    cur[i] = v;
  }
  if (i == NN) off[NN] = NE;
}

// ---------------- fat kernel: place ∥ prepx ∥ prepB ∥ pooled-zero ----------

constexpr int FB_PLACE = (NE + 255) / 256;      // 3125
constexpr int FB_PREPX = NN / 2;                // 50000 (2 nodes/block)
constexpr int FB_PREPB = 256;
constexpr int FB_POOL  = (NG * F2 + 255) / 256; // 115

__global__ __launch_bounds__(256) void k_fatB(
    const int* __restrict__ src, const int* __restrict__ dst,
    int* __restrict__ cur, int* __restrict__ srcs,
    const float* __restrict__ x, const float* __restrict__ dinv,
    unsigned short* __restrict__ xd,
    const float* __restrict__ W1, const float* __restrict__ W2,
    unsigned short* __restrict__ B1, unsigned short* __restrict__ B2,
    float* __restrict__ pooled) {
  int b = blockIdx.x, t = threadIdx.x;
  if (b < FB_PLACE) {
    int e = b * 256 + t;
    if (e < NE) {
      int p = atomicAdd(&cur[dst[e]], 1);
      srcs[p] = src[e];
    }
  } else if (b < FB_PLACE + FB_PREPX) {
    int bb = b - FB_PLACE;
    int n = bb * 2 + (t >> 7);
    int f = t & 127;
    float v = (f < F0) ? x[(size_t)n * F0 + f] * dinv[n] : 0.0f;
    xd[(size_t)n * 128 + f] = f2h_bits(v);
  } else if (b < FB_PLACE + FB_PREPX + FB_PREPB) {
    int bb = b - (FB_PLACE + FB_PREPX);
    if (bb < 128) {  // B1: [256 n][128 k] fp16, two n-rows per block
      int n = bb * 2 + (t >> 7), k = t & 127;
      float v = (k < F0 && n < F1) ? W1[(size_t)k * F1 + n] : 0.0f;
      B1[(size_t)n * 128 + k] = f2h_bits(v);
    } else {         // B2: [128 n][256 k] fp16
      int n = bb - 128, k = t;
      float v = (k < F1 && n < F2) ? W2[(size_t)k * F2 + n] : 0.0f;
      B2[(size_t)n * 256 + k] = f2h_bits(v);
    }
  } else {
    int bb = b - (FB_PLACE + FB_PREPX + FB_PREPB);
    int i = bb * 256 + t;
    if (i < NG * F2) pooled[i] = 0.0f;
  }
}

// ---------------- wave-per-node gather: 16 edge slots/iter, 4 loads in flight

template <bool POOL>
__global__ __launch_bounds__(256) void k_gatherw(
    const unsigned short* __restrict__ tab, const float* __restrict__ dinv,
    const int* __restrict__ off, const int* __restrict__ srcs,
    const float* __restrict__ b2, const int* __restrict__ batch,
    unsigned short* __restrict__ outh, float* __restrict__ pooled) {
  __shared__ float smax[4][128];
  __shared__ int sg[4];
  int w = threadIdx.x >> 6, lane = threadIdx.x & 63;
  int n = blockIdx.x * 4 + w;
  int grp = lane >> 4, sub = lane & 15;
  int fb = sub * 8;

  float acc[8] = {0.f, 0.f, 0.f, 0.f, 0.f, 0.f, 0.f, 0.f};
  int j0 = off[n], j1 = off[n + 1];  // slots j0..j1, self at j1
  for (int base = j0; base <= j1; base += 16) {
    int row[4];
    u16x8 v[4];
    bool has[4];
#pragma unroll
    for (int c = 0; c < 4; ++c) {
      int je = base + c * 4 + grp;
      row[c] = (je < j1) ? srcs[je] : ((je == j1) ? n : -1);
      has[c] = row[c] >= 0;
    }
#pragma unroll
    for (int c = 0; c < 4; ++c)
      if (has[c]) v[c] = *(const u16x8*)&tab[(size_t)row[c] * 128 + fb];
#pragma unroll
    for (int c = 0; c < 4; ++c)
      if (has[c]) {
#pragma unroll
        for (int u = 0; u < 8; ++u) acc[u] += h_bits2f(v[c][u]);
      }
  }
#pragma unroll
  for (int u = 0; u < 8; ++u) {
    acc[u] += __shfl_xor(acc[u], 16);
    acc[u] += __shfl_xor(acc[u], 32);
  }
  float dn = dinv[n];

  if constexpr (!POOL) {
    if (grp == 0) {
      u16x8 o;
#pragma unroll
      for (int u = 0; u < 8; ++u) o[u] = f2h_bits(acc[u] * dn);
      *(u16x8*)&outh[(size_t)n * 128 + fb] = o;
    }
  } else {
    if (grp == 0) {
#pragma unroll
      for (int u = 0; u < 8; ++u) {
        int f = fb + u;
        float bb = (f < F2) ? b2[f] : 0.0f;
        smax[w][f] = fmaxf(acc[u] * dn + bb, 0.0f);
      }
      if (sub == 0) sg[w] = batch[n];
    }
    __syncthreads();
    int t = threadIdx.x;
    if (t < 128) {
      int g0 = sg[0];
      bool same = (sg[1] == g0) & (sg[2] == g0) & (sg[3] == g0);
      if (same) {
        float m = fmaxf(fmaxf(smax[0][t], smax[1][t]),
                        fmaxf(smax[2][t], smax[3][t]));
        if (t < F2 && m > 0.0f)
          atomicMax((int*)&pooled[g0 * F2 + t], __float_as_int(m));
      } else {
        for (int ww = 0; ww < 4; ++ww) {
          float m = smax[ww][t];
          if (t < F2 && m > 0.0f)
            atomicMax((int*)&pooled[sg[ww] * F2 + t], __float_as_int(m));
        }
      }
    }
  }
}

// ---------------- fused double GEMM v8: single-fp16 weights ----------------
// td = (relu(aggX@W1t^T + b1) @ W2t^T) * dinv.  Interleaved per-half schedule:
// rd0-1 s1(h0)->h1half, rd2-3 s2 partial-K(h0), rd4-5 s1(h1), rd6-7 s2(h1).
// Single fp16 W (drop lo term: adds ~1e-4 rms vs fp16-activation floor).
// LDS: As 16K + h1half 16K + Bs 16K = 48 KB -> 3 blocks/CU (12 waves).
// B reg-prefetch 1 round ahead + bar_nodrain (loads survive barriers).
// Swizzle byte^=(row&7)<<4 (verified r13-r17).

__global__ __launch_bounds__(256, 3) void k_fused(
    const unsigned short* __restrict__ A,     // [MPAD][128] fp16
    const unsigned short* __restrict__ B1,    // [256][128] fp16
    const unsigned short* __restrict__ B2,    // [128][256] fp16
    const float* __restrict__ b1, const float* __restrict__ dscale,
    unsigned short* __restrict__ td) {        // [MPAD][128] fp16
  __shared__ char lds[49152];
  char* AsB = lds;            // 16384 B: 64 rows x 256 B (A tile, swizzled)
  char* h1B = lds + 16384;    // 16384 B: 64 rows x 256 B (h1 half, swizzled)
  char* Bs  = lds + 32768;    // 16384 B: 128 rows x 128 B (B chunk, swizzled)

  const int t = threadIdx.x;
  const int m0 = blockIdx.x * 64;
  const int lane = t & 63, w = t >> 6;
  const int r = lane & 15;
  const int kq = lane >> 4;          // k-quarter 0..3
  const int kb16 = kq * 16;          // byte offset of lane's 16B k-frag in 128B
  const int rq = kq * 4;
  const int wc = w * 32;             // wave's 32-col slice
  const int swr = (r & 7) << 4;      // MFMA-read swizzle
  const int arow = t >> 2, aseg = t & 3, aswz = (arow & 7) << 4;
  const int brow = t >> 1, bseg = t & 1, bswz = (brow & 7) << 4;

  // ---------- prologue: stage A tile once; issue B(round 0) ----------
  {
    size_t ga = (size_t)(m0 + arow) * 128 + aseg * 32;
#pragma unroll
    for (int v = 0; v < 4; ++v) {
      u16x8 d = *(const u16x8*)&A[ga + v * 8];
      *(u16x8*)(AsB + arow * 256 + ((aseg * 64 + v * 16) ^ aswz)) = d;
    }
  }
  u16x8 ph[4];
  {
    size_t gb = (size_t)brow * 128 + bseg * 32;  // B1, h=0, kc=0
#pragma unroll
    for (int v = 0; v < 4; ++v) ph[v] = *(const u16x8*)&B1[gb + v * 8];
  }

  f32x4 acc1[4][2], acc2[4][2];
#pragma unroll
  for (int i = 0; i < 4; ++i)
#pragma unroll
    for (int j = 0; j < 2; ++j) {
      acc1[i][j] = (f32x4){0.f, 0.f, 0.f, 0.f};
      acc2[i][j] = (f32x4){0.f, 0.f, 0.f, 0.f};
    }

  // ---------- 8 rounds: h=rd>>2, phase=(rd>>1)&1 (0:s1,1:s2), kc=rd&1 ------
#pragma unroll
  for (int rd = 0; rd < 8; ++rd) {
    const int h = rd >> 2, phase = (rd >> 1) & 1, kc = rd & 1;
    bar_nodrain();  // prev Bs readers done; rd0: fences AsB; rd2/6: fences h1B
#pragma unroll
    for (int v = 0; v < 4; ++v)
      *(u16x8*)(Bs + brow * 128 + ((bseg * 64 + v * 16) ^ bswz)) = ph[v];
    if (rd < 7) {
      const int nr = rd + 1, nh = nr >> 2, nph = (nr >> 1) & 1, nkc = nr & 1;
      const unsigned short* G = (nph == 0) ? B1 : B2;
      const size_t gb = (nph == 0)
          ? (size_t)(nh * 128 + brow) * 128 + nkc * 64 + bseg * 32
          : (size_t)brow * 256 + nh * 128 + nkc * 64 + bseg * 32;
#pragma unroll
      for (int v = 0; v < 4; ++v) ph[v] = *(const u16x8*)&G[gb + v * 8];
    }
    bar_nodrain();  // Bs ready (lgkm only; prefetch stays in flight)

    if (phase == 0) {
      // ----- stage 1: acc1 += A[:, kc*64..] @ B1[h*128.., kc*64..] -----
#pragma unroll
      for (int ks = 0; ks < 2; ++ks) {
        f16x8 av[4], bv[2];
#pragma unroll
        for (int i = 0; i < 4; ++i)
          av[i] = *(const f16x8*)(AsB + (i * 16 + r) * 256 +
                                  ((kc * 128 + ks * 64 + kb16) ^ swr));
#pragma unroll
        for (int j = 0; j < 2; ++j)
          bv[j] = *(const f16x8*)(Bs + (wc + j * 16 + r) * 128 +
                                  ((ks * 64 + kb16) ^ swr));
#pragma unroll
        for (int i = 0; i < 4; ++i)
#pragma unroll
          for (int j = 0; j < 2; ++j)
            acc1[i][j] = __builtin_amdgcn_mfma_f32_16x16x32_f16(av[i], bv[j], acc1[i][j], 0, 0, 0);
      }
      if (kc == 1) {  // rd==1 or rd==5: finish this h-half -> h1B
        // C/D layout: col = lane&15 (n), row = kq*4 + q (m)  [m89/m91]
#pragma unroll
        for (int i = 0; i < 4; ++i)
#pragma unroll
          for (int j = 0; j < 2; ++j) {
            const int nl = wc + j * 16 + r;
            const int n = h * 128 + nl;
            const bool val = n < F1;
            const float bb = val ? b1[n] : 0.0f;
#pragma unroll
            for (int q = 0; q < 4; ++q) {
              const int ml = i * 16 + rq + q;
              const float v = val ? fmaxf(acc1[i][j][q] + bb, 0.0f) : 0.0f;
              *(unsigned short*)(h1B + ml * 256 + ((nl * 2) ^ ((ml & 7) << 4))) = f2h_bits(v);
            }
          }
#pragma unroll
        for (int i = 0; i < 4; ++i)
#pragma unroll
          for (int j = 0; j < 2; ++j) acc1[i][j] = (f32x4){0.f, 0.f, 0.f, 0.f};
      }
    } else {
      // ----- stage 2 partial-K: acc2 += h1half @ B2[:, h*128 + kc*64..] ----
#pragma unroll
      for (int ks = 0; ks < 2; ++ks) {
        f16x8 ah[4], bv[2];
#pragma unroll
        for (int i = 0; i < 4; ++i) {
          const int row = i * 16 + r;
          ah[i] = *(const f16x8*)(h1B + row * 256 +
                                  ((kc * 128 + ks * 64 + kb16) ^ swr));
        }
#pragma unroll
        for (int j = 0; j < 2; ++j)
          bv[j] = *(const f16x8*)(Bs + (wc + j * 16 + r) * 128 +
                                  ((ks * 64 + kb16) ^ swr));
#pragma unroll
        for (int i = 0; i < 4; ++i)
#pragma unroll
          for (int j = 0; j < 2; ++j)
            acc2[i][j] = __builtin_amdgcn_mfma_f32_16x16x32_f16(ah[i], bv[j], acc2[i][j], 0, 0, 0);
      }
    }
  }

  // epilogue: scale by dinv[m], stage fp16 tile into h1B (swizzled), store
  __syncthreads();  // all h1B reads done
#pragma unroll
  for (int i = 0; i < 4; ++i)
#pragma unroll
    for (int j = 0; j < 2; ++j) {
      const int nl = wc + j * 16 + r;
#pragma unroll
      for (int q = 0; q < 4; ++q) {
        const int ml = i * 16 + rq + q;
        const float v = acc2[i][j][q] * dscale[m0 + ml];
        *(unsigned short*)(h1B + ml * 256 + ((nl * 2) ^ ((ml & 7) << 4))) = f2h_bits(v);
      }
    }
  __syncthreads();
  {
    const int row = t >> 2, seg = t & 3;
    const int swz = (row & 7) << 4;
    const size_t dst = (size_t)(m0 + row) * 128 + seg * 32;
#pragma unroll
    for (int v = 0; v < 4; ++v) {
      u16x8 d = *(const u16x8*)(h1B + row * 256 + ((seg * 64 + v * 16) ^ swz));
      *(u16x8*)&td[dst + v * 8] = d;
    }
  }
}

// ---------------- tiny MLP head: 115 -> 64 -> 32 -> 1 ----------------

__global__ void k_mlp(const float* __restrict__ pooled,
                      const float* __restrict__ Wg, const float* __restrict__ bg,
                      const float* __restrict__ Wf, const float* __restrict__ bf,
                      const float* __restrict__ Wo, const float* __restrict__ bo,
                      float* __restrict__ out) {
  __shared__ float sp[F2];
  __shared__ float sg[64];
  __shared__ float sf[32];
  int g = blockIdx.x, t = threadIdx.x;
  for (int f = t; f < F2; f += 64) sp[f] = pooled[g * F2 + f];
  __syncthreads();
  float a = bg[t];
  for (int k = 0; k < F2; ++k) a += sp[k] * Wg[k * 64 + t];
  sg[t] = fmaxf(a, 0.0f);
  __syncthreads();
  if (t < 32) {
    float c = bf[t];
    for (int k = 0; k < 64; ++k) c += sg[k] * Wf[k * 32 + t];
    sf[t] = fmaxf(c, 0.0f);
  }
  __syncthreads();
  if (t == 0) {
    float c = bo[0];
    for (int k = 0; k < 32; ++k) c += sf[k] * Wo[k];
    out[g] = c;
  }
}

// ---------------- launch ----------------

extern "C" void kernel_launch(void* const* d_in, const int* in_sizes, int n_in,
                              void* d_out, int out_size, void* d_ws, size_t ws_size,
                              hipStream_t stream) {
  const float* x  = (const float*)d_in[0];
  const int* ei   = (const int*)d_in[1];
  const int* batch = (const int*)d_in[2];
  const float* W1 = (const float*)d_in[3];
  const float* b1 = (const float*)d_in[4];
  const float* W2 = (const float*)d_in[5];
  const float* b2 = (const float*)d_in[6];
  const float* Wg = (const float*)d_in[7];
  const float* bg = (const float*)d_in[8];
  const float* Wf = (const float*)d_in[9];
  const float* bf = (const float*)d_in[10];
  const float* Wo = (const float*)d_in[11];
  const float* bo = (const float*)d_in[12];
  const int* src = ei;
  const int* dst = ei + NE;

  char* p = (char*)d_ws;
  auto alloc4 = [&](size_t units) { void* r = p; p += units * 4; return r; };
  float* dinv  = (float*)alloc4(100224);
  int* cnt     = (int*)alloc4(100224);
  int* off     = (int*)alloc4(100352);
  int* cur     = (int*)alloc4(100224);
  int* bsum    = (int*)alloc4(128);
  int* srcs    = (int*)alloc4(NE);
  unsigned short* xd   = (unsigned short*)alloc4((size_t)NN * 128 / 2);    // 25.6MB
  unsigned short* aggX = (unsigned short*)alloc4((size_t)MPAD * 128 / 2);  // 25.6MB
  unsigned short* td   = (unsigned short*)alloc4((size_t)MPAD * 128 / 2);  // 25.6MB
  unsigned short* Bt1  = (unsigned short*)alloc4(256 * 128 / 2);
  unsigned short* Bt2  = (unsigned short*)alloc4(128 * 256 / 2);
  float* pooled = (float*)alloc4((size_t)NG * F2);

  hipMemsetAsync(cnt, 0, 100224 * sizeof(int), stream);

  // CSR count + scan (scan1 also emits dinv)
  k_count<<<(NE + 255) / 256, 256, 0, stream>>>(dst, cnt);
  k_scan1<<<NB, SCAN_T, 0, stream>>>(cnt, off, bsum, dinv);
  k_scan3<<<(NN + 256) / 256, 256, 0, stream>>>(off, bsum, cur);

  // fat: place ∥ prepx ∥ prepB ∥ pooled-zero (independent, one launch)
  k_fatB<<<FB_PLACE + FB_PREPX + FB_PREPB + FB_POOL, 256, 0, stream>>>(
      src, dst, cur, srcs, x, dinv, xd, W1, W2, Bt1, Bt2, pooled);

  // layer 1 aggregation -> aggX fp16
  k_gatherw<false><<<NN / 4, 256, 0, stream>>>(xd, dinv, off, srcs,
                                               nullptr, nullptr, aggX, nullptr);

  // fused conv1-GEMM + conv2-GEMM (h1 never leaves LDS) -> td fp16
  k_fused<<<MPAD / 64, 256, 0, stream>>>(aggX, Bt1, Bt2, b1, dinv, td);

  // layer 2 aggregation fused with relu(+b2) + per-graph max pool
  k_gatherw<true><<<NN / 4, 256, 0, stream>>>(td, dinv, off, srcs,
                                              b2, batch, nullptr, pooled);

  // head MLP
  k_mlp<<<NG, 64, 0, stream>>>(pooled, Wg, bg, Wf, bf, Wo, bo, (float*)d_out);
}